// Round 1
// baseline (2087.048 us; speedup 1.0000x reference)
//
#include <hip/hip_runtime.h>
#include <hip/hip_bf16.h>
#include <cstdint>
#include <cstddef>

#define DEVINL __device__ __forceinline__

typedef __attribute__((ext_vector_type(8))) short bf16x8;
typedef __attribute__((ext_vector_type(4))) float f32x4;

// ---------- helpers ----------
DEVINL float bf2f(unsigned short u){
  union { unsigned u32; float f; } cv; cv.u32 = ((unsigned)u) << 16; return cv.f;
}
DEVINL unsigned short f2bf(float f){
  union { float f; unsigned u32; } cv; cv.f = f;
  unsigned u = cv.u32;
  return (unsigned short)((u + 0x7FFFu + ((u >> 16) & 1u)) >> 16);  // RNE
}
DEVINL float softplusf(float x){ return x > 20.f ? x : log1pf(expf(x)); }

// async global->LDS, 16B per lane (CK-style casts)
DEVINL void g2l16(const void* gptr, void* ldsptr){
  __builtin_amdgcn_global_load_lds(
      (const __attribute__((address_space(1))) unsigned int*)gptr,
      (__attribute__((address_space(3))) unsigned int*)(uintptr_t)ldsptr,
      16, 0, 0);
}

// ---------- f32 -> bf16 conversion ----------
__global__ __launch_bounds__(256) void k_f32_to_bf16(
    const float* __restrict__ in, unsigned short* __restrict__ out, long n)
{
  long i = ((long)blockIdx.x * 256 + threadIdx.x) * 4;
  if (i + 3 < n){
    float4 v = *(const float4*)(in + i);
    unsigned long long pk =
        (unsigned long long)f2bf(v.x)
      | ((unsigned long long)f2bf(v.y) << 16)
      | ((unsigned long long)f2bf(v.z) << 32)
      | ((unsigned long long)f2bf(v.w) << 48);
    *(unsigned long long*)(out + i) = pk;
  }
}

// ---------- bf16 GEMM, both operands K-major (A: MxK, Bt: NrowsxK), C = A * Bt^T ----------
// 128x128 tile, BK=32, 4 waves (2x2), 16x16x32 MFMA, m97-style structure.
template<bool OUT_BF16>
__global__ __launch_bounds__(256) void k_gemm_bt(
    const unsigned short* __restrict__ A,
    const unsigned short* __restrict__ Bt,
    void* __restrict__ Cout,
    int K, int Nrows, int Npad, int tiles_n)
{
  __shared__ unsigned short Asub[128*32];
  __shared__ unsigned short Bsub[128*32];
  const int tid = threadIdx.x;
  const int rt = blockIdx.x / tiles_n, ct = blockIdx.x % tiles_n;
  const int lane = tid & 63, wave = tid >> 6;
  const int wr = wave >> 1, wc = wave & 1;

  // staging: thread t loads 16B; row = t>>2 (within 64-row half), col elems (t&3)*8
  const int sr = tid >> 2;
  const int sc = (tid & 3) * 8;
  const size_t a_r0 = (size_t)(rt*128 + sr) * K + sc;
  const size_t a_r1 = a_r0 + (size_t)64 * K;
  int b0 = ct*128 + sr;      if (b0 > Nrows-1) b0 = Nrows-1;   // clamp (padded cols junk)
  int b1 = ct*128 + 64 + sr; if (b1 > Nrows-1) b1 = Nrows-1;
  const size_t b_r0 = (size_t)b0 * K + sc;
  const size_t b_r1 = (size_t)b1 * K + sc;

  char* aL0 = (char*)Asub + tid*16;
  char* aL1 = (char*)Asub + 4096 + tid*16;
  char* bL0 = (char*)Bsub + tid*16;
  char* bL1 = (char*)Bsub + 4096 + tid*16;

  f32x4 acc[4][4] = {};
  const int fr = lane & 15;         // fragment row (m for A, n for B)
  const int fk = (lane >> 4) * 8;   // k sub-offset

  for (int k0 = 0; k0 < K; k0 += 32){
    g2l16(A  + a_r0 + k0, aL0);
    g2l16(A  + a_r1 + k0, aL1);
    g2l16(Bt + b_r0 + k0, bL0);
    g2l16(Bt + b_r1 + k0, bL1);
    asm volatile("s_waitcnt vmcnt(0)" ::: "memory");
    __syncthreads();

    bf16x8 af[4], bfr[4];
    #pragma unroll
    for (int i = 0; i < 4; i++){
      af[i]  = *(const bf16x8*)&Asub[(wr*64 + i*16 + fr)*32 + fk];
      bfr[i] = *(const bf16x8*)&Bsub[(wc*64 + i*16 + fr)*32 + fk];
    }
    #pragma unroll
    for (int mi = 0; mi < 4; mi++)
      #pragma unroll
      for (int ni = 0; ni < 4; ni++)
        acc[mi][ni] = __builtin_amdgcn_mfma_f32_16x16x32_bf16(af[mi], bfr[ni], acc[mi][ni], 0, 0, 0);
    __syncthreads();
  }

  // epilogue: C/D layout col=lane&15, row=(lane>>4)*4+reg
  const int er = (lane >> 4) * 4;
  const int ec = lane & 15;
  #pragma unroll
  for (int mi = 0; mi < 4; mi++){
    #pragma unroll
    for (int ni = 0; ni < 4; ni++){
      const int row = rt*128 + wr*64 + mi*16 + er;
      const int col = ct*128 + wc*64 + ni*16 + ec;
      #pragma unroll
      for (int r = 0; r < 4; r++){
        if (OUT_BF16)
          ((unsigned short*)Cout)[(size_t)(row+r)*Npad + col] = f2bf(acc[mi][ni][r]);
        else
          ((float*)Cout)[(size_t)(row+r)*Npad + col] = acc[mi][ni][r];
      }
    }
  }
}

// ---------- per-(b,l,h) scalars: DT, decay, lam ----------
__global__ __launch_bounds__(256) void k_prep_scalars(
    const unsigned short* __restrict__ proj, const float* __restrict__ dt_bias,
    float* __restrict__ DTb, float* __restrict__ decayb, float* __restrict__ lamb)
{
  int idx = blockIdx.x*256 + threadIdx.x;   // row*64 + h, total 131072
  int h = idx & 63, row = idx >> 6;
  size_t base = (size_t)row * 8704;
  float dd_dt = bf2f(proj[base + 8448 + h]);
  float dd_A  = bf2f(proj[base + 8512 + h]);
  float trap  = bf2f(proj[base + 8576 + h]);
  float DT = softplusf(dd_dt + dt_bias[h]);
  float A  = -fmaxf(softplusf(dd_A), 1e-4f);
  DTb[idx]    = DT;
  decayb[idx] = expf(A * DT);
  lamb[idx]   = 1.f / (1.f + expf(-trap));
}

// ---------- rmsnorm of Braw/Craw rows (N=128), weight applied ----------
__global__ __launch_bounds__(128) void k_rmsnorm(
    const unsigned short* __restrict__ proj, const float* __restrict__ Bw,
    const float* __restrict__ Cw, float* __restrict__ Bbase, float* __restrict__ Cbase)
{
  int row = blockIdx.x, n = threadIdx.x;
  size_t base = (size_t)row * 8704;
  float bv = bf2f(proj[base + 8192 + n]);
  float cv = bf2f(proj[base + 8320 + n]);
  float sb = bv*bv, sc = cv*cv;
  #pragma unroll
  for (int m = 1; m < 64; m <<= 1){ sb += __shfl_xor(sb, m, 64); sc += __shfl_xor(sc, m, 64); }
  __shared__ float red[4];
  if ((n & 63) == 0){ red[(n>>6)*2] = sb; red[(n>>6)*2+1] = sc; }
  __syncthreads();
  sb = red[0] + red[2];
  sc = red[1] + red[3];
  float rb = rsqrtf(sb*(1.f/128.f) + 1e-5f);
  float rc = rsqrtf(sc*(1.f/128.f) + 1e-5f);
  Bbase[row*128 + n] = bv*rb*Bw[n];
  Cbase[row*128 + n] = cv*rc*Cw[n];
}

// ---------- phase cumsum + cos/sin tables (bf16) ----------
// 64 blocks x 64 threads: each thread owns one (b,h,na) sequence, serial over L
__global__ __launch_bounds__(64) void k_phase(
    const unsigned short* __restrict__ proj, const float* __restrict__ DTb,
    unsigned short* __restrict__ cosb, unsigned short* __restrict__ sinb)
{
  int b = blockIdx.x >> 5, hp = blockIdx.x & 31;
  int h = hp*2 + (threadIdx.x >> 5), na = threadIdx.x & 31;
  float ph = 0.f;
  for (int t = 0; t < 1024; t++){
    int row = b*1024 + t;
    float ang = bf2f(proj[(size_t)row*8704 + 8640 + na]);
    float dt  = DTb[row*64 + h];
    ph = fmaf(ang, dt, ph);
    float s, c;
    sincosf(ph, &s, &c);
    size_t o = ((size_t)row*64 + h)*32 + na;
    cosb[o] = f2bf(c);
    sinb[o] = f2bf(s);
  }
}

// ---------- sequential recurrence over L ----------
// one block per (b,h); 1024 threads: thread = p*16 + g, owns n in [g*8, g*8+8)
__global__ __launch_bounds__(1024) void k_scan(
    const unsigned short* __restrict__ proj,
    const float* __restrict__ Bbase, const float* __restrict__ Cbase,
    const float* __restrict__ Bbias, const float* __restrict__ Cbias,
    const unsigned short* __restrict__ cosb, const unsigned short* __restrict__ sinb,
    const float* __restrict__ DTb, const float* __restrict__ decayb,
    const float* __restrict__ lamb, const float* __restrict__ Dv,
    unsigned short* __restrict__ ybf)
{
  const int b = blockIdx.x >> 6;
  const int h = blockIdx.x & 63;
  const int tid = threadIdx.x;
  const int p = tid >> 4, g = tid & 15;

  __shared__ float Braws[128], Craws[128], Bhs[128], Chs[128];
  __shared__ float us[64], xs[64], zs[64], scal[2];

  float hreg[8], Greg[8];
  #pragma unroll
  for (int e = 0; e < 8; e++){ hreg[e] = 0.f; Greg[e] = 0.f; }
  const float Dh = Dv[h];

  for (int t = 0; t < 1024; t++){
    const int row = b*1024 + t;
    // ---- stage raw inputs ----
    if (tid < 128){
      Braws[tid] = Bbase[row*128 + tid] + Bbias[h*128 + tid];
    } else if (tid < 256){
      int n = tid - 128;
      Craws[n] = Cbase[row*128 + n] + Cbias[h*128 + n];
    } else if (tid < 320){
      int pp = tid - 256;
      float x = bf2f(proj[(size_t)row*8704 + 4096 + h*64 + pp]);
      xs[pp] = x;
      us[pp] = x * DTb[row*64 + h];
    } else if (tid < 384){
      int pp = tid - 320;
      zs[pp] = bf2f(proj[(size_t)row*8704 + h*64 + pp]);
    } else if (tid == 384){
      scal[0] = decayb[row*64 + h];
      scal[1] = lamb[row*64 + h];
    }
    __syncthreads();
    // ---- rope ----
    if (tid < 32){
      float c = bf2f(cosb[((size_t)row*64 + h)*32 + tid]);
      float s = bf2f(sinb[((size_t)row*64 + h)*32 + tid]);
      float v1 = Braws[tid], v2 = Braws[tid+32];
      Bhs[tid]    = v1*c - v2*s;
      Bhs[tid+32] = v1*s + v2*c;
    } else if (tid < 64){
      int na = tid - 32;
      float c = bf2f(cosb[((size_t)row*64 + h)*32 + na]);
      float s = bf2f(sinb[((size_t)row*64 + h)*32 + na]);
      float v1 = Craws[na], v2 = Craws[na+32];
      Chs[na]    = v1*c - v2*s;
      Chs[na+32] = v1*s + v2*c;
    } else if (tid < 128){
      Bhs[tid] = Braws[tid];          // n in [64,128)
    } else if (tid < 192){
      Chs[tid-64] = Craws[tid-64];    // n in [64,128)
    }
    __syncthreads();
    // ---- recurrence update ----
    const float dec = scal[0], lam = scal[1];
    const float s2 = 1.f - lam, s3 = lam * dec;
    const float up = us[p];
    float y = 0.f;
    #pragma unroll
    for (int e = 0; e < 8; e++){
      float Bv = Bhs[g*8+e], Cv = Chs[g*8+e];
      float Gn = up * Bv;
      hreg[e] = dec*hreg[e] + s2*Gn + s3*Greg[e];
      Greg[e] = Gn;
      y = fmaf(hreg[e], Cv, y);
    }
    y += __shfl_xor(y, 1, 16);
    y += __shfl_xor(y, 2, 16);
    y += __shfl_xor(y, 4, 16);
    y += __shfl_xor(y, 8, 16);
    if (g == 0){
      float z = zs[p];
      float sl = z / (1.f + expf(-z));
      float o = (y + Dh*xs[p]) * sl;
      ybf[((size_t)row*64 + h)*64 + p] = f2bf(o);
    }
    __syncthreads();
  }
}

// ---------- launch ----------
extern "C" void kernel_launch(void* const* d_in, const int* in_sizes, int n_in,
                              void* d_out, int out_size, void* d_ws, size_t ws_size,
                              hipStream_t stream)
{
  const float* hs    = (const float*)d_in[0];
  const float* w1    = (const float*)d_in[1];
  const float* dtb   = (const float*)d_in[2];
  const float* Bbias = (const float*)d_in[3];
  const float* Cbias = (const float*)d_in[4];
  const float* Bw    = (const float*)d_in[5];
  const float* Cw    = (const float*)d_in[6];
  const float* Dv    = (const float*)d_in[7];
  const float* wo    = (const float*)d_in[8];
  float* out = (float*)d_out;
  char* ws = (char*)d_ws;

  // ws layout (regions overlapped by lifetime):
  //   [0, 35.65M)   projbf  (2048 x 8704 bf16)              live gemm1 -> scan
  //   [35.65M, +35.52M) W1bf (8672x2048 bf16); after gemm1 reused as Wobf(16.78M)+ybf(16.78M)
  //   [71.17M, +8.39M)  hsbf (2048x2048 bf16); after gemm1 reused as cosb (2048*64*32 bf16)
  //   [79.56M, +8.39M)  sinb
  //   then DTb/decayb/lamb (0.5M each f32), Bbase/Cbase (1.05M each f32)
  unsigned short* projbf = (unsigned short*)(ws + 0UL);
  unsigned short* W1bf   = (unsigned short*)(ws + 35651584UL);
  unsigned short* Wobf   = W1bf;
  unsigned short* ybf    = (unsigned short*)(ws + 35651584UL + 16777216UL);
  unsigned short* hsbf   = (unsigned short*)(ws + 71172096UL);
  unsigned short* cosb   = hsbf;
  unsigned short* sinb   = (unsigned short*)(ws + 79560704UL);
  float* DTb    = (float*)(ws + 87949312UL);
  float* decayb = (float*)(ws + 88473600UL);
  float* lamb   = (float*)(ws + 88997888UL);
  float* Bbase  = (float*)(ws + 89522176UL);
  float* Cbase  = (float*)(ws + 90570752UL);
  if (ws_size < 91619328UL) return;  // insufficient scratch -> visible failure

  (void)in_sizes; (void)n_in; (void)out_size;

  // 1-2: weight/activation conversion to bf16
  k_f32_to_bf16<<<17344, 256, 0, stream>>>(w1, W1bf, 17760256L);
  k_f32_to_bf16<<<4096,  256, 0, stream>>>(hs, hsbf, 4194304L);
  // 3: proj = hs @ W1^T  (M=2048, K=2048, N=8672 padded 8704)
  k_gemm_bt<true><<<16*68, 256, 0, stream>>>(hsbf, W1bf, projbf, 2048, 8672, 8704, 68);
  // 4-6: scalars, rmsnorm, phase tables
  k_prep_scalars<<<512, 256, 0, stream>>>(projbf, dtb, DTb, decayb, lamb);
  k_rmsnorm<<<2048, 128, 0, stream>>>(projbf, Bw, Cw, Bbase, Cbase);
  k_phase<<<64, 64, 0, stream>>>(projbf, DTb, cosb, sinb);
  // 7: out-proj weights to bf16 (reuses W1bf region — after gemm1)
  k_f32_to_bf16<<<8192, 256, 0, stream>>>(wo, Wobf, 8388608L);
  // 8: sequential recurrence, writes gated y (bf16)
  k_scan<<<128, 1024, 0, stream>>>(projbf, Bbase, Cbase, Bbias, Cbias,
                                   cosb, sinb, DTb, decayb, lamb, Dv, ybf);
  // 9: out = y @ Wo^T  (M=2048, K=4096, N=2048), f32 output
  k_gemm_bt<false><<<16*16, 256, 0, stream>>>(ybf, Wobf, out, 4096, 2048, 2048, 16);
}

// Round 2
// 536.195 us; speedup vs baseline: 3.8923x; 3.8923x over previous
//
#include <hip/hip_runtime.h>
#include <hip/hip_bf16.h>
#include <cstdint>
#include <cstddef>

#define DEVINL __device__ __forceinline__

typedef __attribute__((ext_vector_type(8))) short bf16x8;
typedef __attribute__((ext_vector_type(4))) float f32x4;

// ---------- helpers ----------
DEVINL float bf2f(unsigned short u){
  union { unsigned u32; float f; } cv; cv.u32 = ((unsigned)u) << 16; return cv.f;
}
DEVINL unsigned short f2bf(float f){
  union { float f; unsigned u32; } cv; cv.f = f;
  unsigned u = cv.u32;
  return (unsigned short)((u + 0x7FFFu + ((u >> 16) & 1u)) >> 16);  // RNE
}
DEVINL float softplusf(float x){ return x > 20.f ? x : log1pf(expf(x)); }

DEVINL void g2l16(const void* gptr, void* ldsptr){
  __builtin_amdgcn_global_load_lds(
      (const __attribute__((address_space(1))) unsigned int*)gptr,
      (__attribute__((address_space(3))) unsigned int*)(uintptr_t)ldsptr,
      16, 0, 0);
}

// swizzled LDS access; all tiles have 256-byte rows (128 bf16 cols)
DEVINL int swzb(int row, int col){ return row*256 + ((col*2) ^ ((row&7)<<4)); }
DEVINL void ldsw_write8(unsigned short* b, int row, int col, bf16x8 v){
  *(bf16x8*)((char*)b + swzb(row,col)) = v;
}
DEVINL bf16x8 ldsw_read8(const unsigned short* b, int row, int col){
  return *(const bf16x8*)((const char*)b + swzb(row,col));
}
DEVINL void ldsw_write1(unsigned short* b, int row, int col, unsigned short v){
  *(unsigned short*)((char*)b + swzb(row,col)) = v;
}
DEVINL unsigned short ldsw_read1(const unsigned short* b, int row, int col){
  return *(const unsigned short*)((const char*)b + swzb(row,col));
}

// ---------- f32 -> bf16 conversion ----------
__global__ __launch_bounds__(256) void k_f32_to_bf16(
    const float* __restrict__ in, unsigned short* __restrict__ out, long n)
{
  long i = ((long)blockIdx.x * 256 + threadIdx.x) * 4;
  if (i + 3 < n){
    float4 v = *(const float4*)(in + i);
    unsigned long long pk =
        (unsigned long long)f2bf(v.x)
      | ((unsigned long long)f2bf(v.y) << 16)
      | ((unsigned long long)f2bf(v.z) << 32)
      | ((unsigned long long)f2bf(v.w) << 48);
    *(unsigned long long*)(out + i) = pk;
  }
}

// ---------- bf16 GEMM, both operands K-major, C = A * Bt^T ----------
template<bool OUT_BF16>
__global__ __launch_bounds__(256) void k_gemm_bt(
    const unsigned short* __restrict__ A,
    const unsigned short* __restrict__ Bt,
    void* __restrict__ Cout,
    int K, int Nrows, int Npad, int tiles_n)
{
  __shared__ unsigned short Asub[128*32];
  __shared__ unsigned short Bsub[128*32];
  const int tid = threadIdx.x;
  const int rt = blockIdx.x / tiles_n, ct = blockIdx.x % tiles_n;
  const int lane = tid & 63, wave = tid >> 6;
  const int wr = wave >> 1, wc = wave & 1;

  const int sr = tid >> 2;
  const int sc = (tid & 3) * 8;
  const size_t a_r0 = (size_t)(rt*128 + sr) * K + sc;
  const size_t a_r1 = a_r0 + (size_t)64 * K;
  int b0 = ct*128 + sr;      if (b0 > Nrows-1) b0 = Nrows-1;
  int b1 = ct*128 + 64 + sr; if (b1 > Nrows-1) b1 = Nrows-1;
  const size_t b_r0 = (size_t)b0 * K + sc;
  const size_t b_r1 = (size_t)b1 * K + sc;

  char* aL0 = (char*)Asub + tid*16;
  char* aL1 = (char*)Asub + 4096 + tid*16;
  char* bL0 = (char*)Bsub + tid*16;
  char* bL1 = (char*)Bsub + 4096 + tid*16;

  f32x4 acc[4][4] = {};
  const int fr = lane & 15;
  const int fk = (lane >> 4) * 8;

  for (int k0 = 0; k0 < K; k0 += 32){
    g2l16(A  + a_r0 + k0, aL0);
    g2l16(A  + a_r1 + k0, aL1);
    g2l16(Bt + b_r0 + k0, bL0);
    g2l16(Bt + b_r1 + k0, bL1);
    asm volatile("s_waitcnt vmcnt(0)" ::: "memory");
    __syncthreads();

    bf16x8 af[4], bfr[4];
    #pragma unroll
    for (int i = 0; i < 4; i++){
      af[i]  = *(const bf16x8*)&Asub[(wr*64 + i*16 + fr)*32 + fk];
      bfr[i] = *(const bf16x8*)&Bsub[(wc*64 + i*16 + fr)*32 + fk];
    }
    #pragma unroll
    for (int mi = 0; mi < 4; mi++)
      #pragma unroll
      for (int ni = 0; ni < 4; ni++)
        acc[mi][ni] = __builtin_amdgcn_mfma_f32_16x16x32_bf16(af[mi], bfr[ni], acc[mi][ni], 0, 0, 0);
    __syncthreads();
  }

  const int er = (lane >> 4) * 4;
  const int ec = lane & 15;
  #pragma unroll
  for (int mi = 0; mi < 4; mi++){
    #pragma unroll
    for (int ni = 0; ni < 4; ni++){
      const int row = rt*128 + wr*64 + mi*16 + er;
      const int col = ct*128 + wc*64 + ni*16 + ec;
      #pragma unroll
      for (int r = 0; r < 4; r++){
        if (OUT_BF16)
          ((unsigned short*)Cout)[(size_t)(row+r)*Npad + col] = f2bf(acc[mi][ni][r]);
        else
          ((float*)Cout)[(size_t)(row+r)*Npad + col] = acc[mi][ni][r];
      }
    }
  }
}

// ---------- per-(b,l,h) scalars -> [b][h][l] layouts ----------
__global__ __launch_bounds__(256) void k_prep_scalars(
    const unsigned short* __restrict__ proj, const float* __restrict__ dt_bias,
    float* __restrict__ DTt, float* __restrict__ logdec, float* __restrict__ lamt)
{
  int idx = blockIdx.x*256 + threadIdx.x;   // (b*1024+l)*64 + h
  int h = idx & 63, row = idx >> 6;
  int b = row >> 10, l = row & 1023;
  size_t base = (size_t)row * 8704;
  float dd_dt = bf2f(proj[base + 8448 + h]);
  float dd_A  = bf2f(proj[base + 8512 + h]);
  float trap  = bf2f(proj[base + 8576 + h]);
  float DT = softplusf(dd_dt + dt_bias[h]);
  float A  = -fmaxf(softplusf(dd_A), 1e-4f);
  size_t o = ((size_t)(b*64 + h))*1024 + l;
  DTt[o]    = DT;
  logdec[o] = A * DT;
  lamt[o]   = 1.f / (1.f + expf(-trap));
}

// ---------- rmsnorm of Braw/Craw rows (N=128) -> bf16 ----------
__global__ __launch_bounds__(128) void k_rmsnorm(
    const unsigned short* __restrict__ proj, const float* __restrict__ Bw,
    const float* __restrict__ Cw, unsigned short* __restrict__ Bb2,
    unsigned short* __restrict__ Cb2)
{
  int row = blockIdx.x, n = threadIdx.x;
  size_t base = (size_t)row * 8704;
  float bv = bf2f(proj[base + 8192 + n]);
  float cv = bf2f(proj[base + 8320 + n]);
  float sb = bv*bv, sc = cv*cv;
  #pragma unroll
  for (int m = 1; m < 64; m <<= 1){ sb += __shfl_xor(sb, m, 64); sc += __shfl_xor(sc, m, 64); }
  __shared__ float red[4];
  if ((n & 63) == 0){ red[(n>>6)*2] = sb; red[(n>>6)*2+1] = sc; }
  __syncthreads();
  sb = red[0] + red[2];
  sc = red[1] + red[3];
  float rb = rsqrtf(sb*(1.f/128.f) + 1e-5f);
  float rc = rsqrtf(sc*(1.f/128.f) + 1e-5f);
  Bb2[row*128 + n] = f2bf(bv*rb*Bw[n]);
  Cb2[row*128 + n] = f2bf(cv*rc*Cw[n]);
}

// ---------- per-chunk inclusive cumsum of logdec + g = 1-lam+lam_next ----------
__global__ __launch_bounds__(256) void k_chunkscan(
    const float* __restrict__ logdec, const float* __restrict__ lamt,
    float* __restrict__ clcb, float* __restrict__ gb)
{
  int bh = blockIdx.x;
  size_t base = (size_t)bh * 1024;
  int tid = threadIdx.x;
  int e0 = tid * 4;
  float v0 = logdec[base+e0], v1 = logdec[base+e0+1], v2 = logdec[base+e0+2], v3 = logdec[base+e0+3];
  float p0 = v0, p1 = p0+v1, p2 = p1+v2, p3 = p2+v3;
  float tot = p3;
  int sub = tid & 31;
  float incl = tot;
  #pragma unroll
  for (int off = 1; off < 32; off <<= 1){
    float u = __shfl_up(incl, off, 32);
    if (sub >= off) incl += u;
  }
  float excl = incl - tot;
  clcb[base+e0]   = excl + p0;
  clcb[base+e0+1] = excl + p1;
  clcb[base+e0+2] = excl + p2;
  clcb[base+e0+3] = excl + p3;
  #pragma unroll
  for (int i = 0; i < 4; i++){
    int l = e0 + i;
    int ln = (l == 1023) ? 1023 : l + 1;
    gb[base+l] = 1.f - lamt[base+l] + lamt[base+ln];
  }
}

// ---------- phase cumsum + cos/sin tables; block per (b,h), 256 thr = 32 na x 8 chunks ----------
__global__ __launch_bounds__(256) void k_phase(
    const unsigned short* __restrict__ proj, const float* __restrict__ DTt,
    unsigned short* __restrict__ cosb, unsigned short* __restrict__ sinb)
{
  int bh = blockIdx.x, b = bh >> 6, h = bh & 63;
  int na = threadIdx.x & 31, c = threadIdx.x >> 5;
  __shared__ float part[8][32];
  const float* dtr = DTt + (size_t)bh * 1024;
  float s = 0.f;
  for (int i = 0; i < 128; i++){
    int l = c*128 + i; int row = b*1024 + l;
    float ang = bf2f(proj[(size_t)row*8704 + 8640 + na]);
    s = fmaf(ang, dtr[l], s);
  }
  part[c][na] = s;
  __syncthreads();
  float off = 0.f;
  for (int cc = 0; cc < c; cc++) off += part[cc][na];
  float ph = off;
  for (int i = 0; i < 128; i++){
    int l = c*128 + i; int row = b*1024 + l;
    float ang = bf2f(proj[(size_t)row*8704 + 8640 + na]);
    ph = fmaf(ang, dtr[l], ph);
    float sn, cs;
    sincosf(ph, &sn, &cs);
    size_t o = ((size_t)row*64 + h)*32 + na;
    cosb[o] = f2bf(cs); sinb[o] = f2bf(sn);
  }
}

// ---------- chunked SSD recurrence: block per (b,h), 8 chunks of 128 ----------
// y_t = sum_{j<=t} v_{t,j} u_j (B_j . C_t) + exp(clc_t) * (C_t . S^T)
// v_{t,j} = exp(clc_t - clc_j)*g_j (j<t), 1-lam_t (j==t); g_j = 1-lam_j+lam_{j+1}
// state: S <- exp(clcEnd)*S + sum_j exp(clcEnd-clc_j)*g_j * u_j (x) B_j   (kept in MFMA acc regs)
__global__ __launch_bounds__(256, 1) void k_chunk(
    const unsigned short* __restrict__ proj,
    const unsigned short* __restrict__ Bb2, const unsigned short* __restrict__ Cb2,
    const float* __restrict__ Bbias, const float* __restrict__ Cbias,
    const unsigned short* __restrict__ cosb, const unsigned short* __restrict__ sinb,
    const float* __restrict__ DTt, const float* __restrict__ clcb,
    const float* __restrict__ gb, const float* __restrict__ lamt,
    const float* __restrict__ Dv, unsigned short* __restrict__ ybf)
{
  const int bh = blockIdx.x, b = bh >> 6, h = bh & 63;
  const int tid = threadIdx.x, lane = tid & 63, wave = tid >> 6;
  const int wr = wave >> 1, wc = wave & 1;
  const int fr = lane & 15, fq = lane >> 4;

  __shared__ __align__(16) unsigned short Cs[128*128];
  __shared__ __align__(16) unsigned short Bs[128*128];   // aliased as P after barrier
  __shared__ __align__(16) unsigned short BTs[128*128];
  __shared__ __align__(16) unsigned short Uts[64*128];   // U^T: [p][j]
  __shared__ __align__(16) unsigned short Sbfs[64*128];  // state bf16: [p][n]
  __shared__ __align__(16) unsigned short zs[128*64];    // z: [t][p], unswizzled
  __shared__ float clcs[128], lams[128], gs[128], wUs[128], expclcs[128], dts[128];
  __shared__ float biasB[128], biasC[128];

  if (tid < 128){ biasB[tid] = Bbias[h*128 + tid]; biasC[tid] = Cbias[h*128 + tid]; }
  const float Dh = Dv[h];
  const size_t shbase = (size_t)bh * 1024;

  f32x4 accS[2][4];
  #pragma unroll
  for (int mi = 0; mi < 2; mi++)
    #pragma unroll
    for (int ni = 0; ni < 4; ni++)
      accS[mi][ni] = (f32x4){0.f,0.f,0.f,0.f};

  for (int c = 0; c < 8; c++){
    const int base = b*1024 + c*128;
    // ---- phase 1: chunk scalars + state -> bf16 LDS ----
    if (tid < 128){
      int l = c*128 + tid;
      clcs[tid] = clcb[shbase + l];
      dts[tid]  = DTt[shbase + l];
      lams[tid] = lamt[shbase + l];
      gs[tid]   = gb[shbase + l];
    }
    #pragma unroll
    for (int mi = 0; mi < 2; mi++)
      #pragma unroll
      for (int ni = 0; ni < 4; ni++)
        #pragma unroll
        for (int r = 0; r < 4; r++)
          ldsw_write1(Sbfs, wr*32+mi*16+fq*4+r, wc*64+ni*16+fr, f2bf(accS[mi][ni][r]));
    __syncthreads();
    if (tid < 128){
      float ce = clcs[127];
      wUs[tid] = __expf(ce - clcs[tid]) * gs[tid];
      expclcs[tid] = __expf(clcs[tid]);
    }
    // ---- phase 2: stage C/B (bias+rope), U^T, z ----
    {
      const int t = tid >> 1, half = tid & 1;
      const int grow = base + t;
      const size_t roff = (size_t)grow*128 + half*64;
      if (half == 0){
        bf16x8 cc[4], sv[4];
        #pragma unroll
        for (int i = 0; i < 4; i++){
          cc[i] = *(const bf16x8*)(cosb + ((size_t)grow*64 + h)*32 + i*8);
          sv[i] = *(const bf16x8*)(sinb + ((size_t)grow*64 + h)*32 + i*8);
        }
        #pragma unroll
        for (int i = 0; i < 4; i++){
          bf16x8 vlo = *(const bf16x8*)(Cb2 + roff + i*8);
          bf16x8 vhi = *(const bf16x8*)(Cb2 + roff + 32 + i*8);
          bf16x8 olo, ohi;
          #pragma unroll
          for (int e = 0; e < 8; e++){
            float a = bf2f((unsigned short)vlo[e]) + biasC[i*8+e];
            float d = bf2f((unsigned short)vhi[e]) + biasC[32+i*8+e];
            float cf = bf2f((unsigned short)cc[i][e]);
            float sf = bf2f((unsigned short)sv[i][e]);
            olo[e] = (short)f2bf(a*cf - d*sf);
            ohi[e] = (short)f2bf(a*sf + d*cf);
          }
          ldsw_write8(Cs, t, i*8, olo);
          ldsw_write8(Cs, t, 32 + i*8, ohi);
        }
        #pragma unroll
        for (int i = 0; i < 4; i++){
          bf16x8 vlo = *(const bf16x8*)(Bb2 + roff + i*8);
          bf16x8 vhi = *(const bf16x8*)(Bb2 + roff + 32 + i*8);
          bf16x8 olo, ohi;
          #pragma unroll
          for (int e = 0; e < 8; e++){
            float a = bf2f((unsigned short)vlo[e]) + biasB[i*8+e];
            float d = bf2f((unsigned short)vhi[e]) + biasB[32+i*8+e];
            float cf = bf2f((unsigned short)cc[i][e]);
            float sf = bf2f((unsigned short)sv[i][e]);
            olo[e] = (short)f2bf(a*cf - d*sf);
            ohi[e] = (short)f2bf(a*sf + d*cf);
          }
          ldsw_write8(Bs, t, i*8, olo);
          ldsw_write8(Bs, t, 32 + i*8, ohi);
          #pragma unroll
          for (int e = 0; e < 8; e++){
            ldsw_write1(BTs, i*8+e, t, (unsigned short)olo[e]);
            ldsw_write1(BTs, 32+i*8+e, t, (unsigned short)ohi[e]);
          }
        }
      } else {
        #pragma unroll
        for (int i = 0; i < 8; i++){
          bf16x8 v = *(const bf16x8*)(Cb2 + roff + i*8);
          bf16x8 o;
          #pragma unroll
          for (int e = 0; e < 8; e++) o[e] = (short)f2bf(bf2f((unsigned short)v[e]) + biasC[64+i*8+e]);
          ldsw_write8(Cs, t, 64 + i*8, o);
        }
        #pragma unroll
        for (int i = 0; i < 8; i++){
          bf16x8 v = *(const bf16x8*)(Bb2 + roff + i*8);
          bf16x8 o;
          #pragma unroll
          for (int e = 0; e < 8; e++) o[e] = (short)f2bf(bf2f((unsigned short)v[e]) + biasB[64+i*8+e]);
          ldsw_write8(Bs, t, 64 + i*8, o);
          #pragma unroll
          for (int e = 0; e < 8; e++) ldsw_write1(BTs, 64+i*8+e, t, (unsigned short)o[e]);
        }
      }
    }
    {
      const int p = tid & 63, jg = tid >> 6;
      #pragma unroll 4
      for (int i = 0; i < 32; i++){
        int j = jg*32 + i;
        size_t pb = (size_t)(base + j) * 8704;
        float x  = bf2f(proj[pb + 4096 + h*64 + p]);
        float zv = bf2f(proj[pb + h*64 + p]);
        ldsw_write1(Uts, p, j, f2bf(x * dts[j]));
        zs[j*64 + p] = f2bf(zv);
      }
    }
    __syncthreads();

    // ---- MFMA1: scores[t][j] = C . B^T ----
    f32x4 acc1[4][4];
    #pragma unroll
    for (int mi = 0; mi < 4; mi++)
      #pragma unroll
      for (int ni = 0; ni < 4; ni++)
        acc1[mi][ni] = (f32x4){0.f,0.f,0.f,0.f};
    #pragma unroll
    for (int ks = 0; ks < 4; ks++){
      bf16x8 af[4], bj[4];
      #pragma unroll
      for (int mi = 0; mi < 4; mi++) af[mi] = ldsw_read8(Cs, wr*64+mi*16+fr, ks*32+fq*8);
      #pragma unroll
      for (int ni = 0; ni < 4; ni++) bj[ni] = ldsw_read8(Bs, wc*64+ni*16+fr, ks*32+fq*8);
      #pragma unroll
      for (int mi = 0; mi < 4; mi++)
        #pragma unroll
        for (int ni = 0; ni < 4; ni++)
          acc1[mi][ni] = __builtin_amdgcn_mfma_f32_16x16x32_bf16(af[mi], bj[ni], acc1[mi][ni], 0,0,0);
    }
    // ---- MFMA3: Ys[t][p] = C . S^T ----
    f32x4 accY[4][2];
    #pragma unroll
    for (int mi = 0; mi < 4; mi++)
      #pragma unroll
      for (int ni = 0; ni < 2; ni++)
        accY[mi][ni] = (f32x4){0.f,0.f,0.f,0.f};
    #pragma unroll
    for (int ks = 0; ks < 4; ks++){
      bf16x8 af[4], sj[2];
      #pragma unroll
      for (int mi = 0; mi < 4; mi++) af[mi] = ldsw_read8(Cs, wr*64+mi*16+fr, ks*32+fq*8);
      #pragma unroll
      for (int ni = 0; ni < 2; ni++) sj[ni] = ldsw_read8(Sbfs, wc*32+ni*16+fr, ks*32+fq*8);
      #pragma unroll
      for (int mi = 0; mi < 4; mi++)
        #pragma unroll
        for (int ni = 0; ni < 2; ni++)
          accY[mi][ni] = __builtin_amdgcn_mfma_f32_16x16x32_bf16(af[mi], sj[ni], accY[mi][ni], 0,0,0);
    }
    // ---- weight epilogue: P = W o scores ----
    unsigned short pr[4][4][4];
    int jj[4]; float clcj[4], gj[4];
    #pragma unroll
    for (int ni = 0; ni < 4; ni++){ jj[ni] = wc*64+ni*16+fr; clcj[ni] = clcs[jj[ni]]; gj[ni] = gs[jj[ni]]; }
    #pragma unroll
    for (int mi = 0; mi < 4; mi++){
      #pragma unroll
      for (int r = 0; r < 4; r++){
        int t = wr*64+mi*16+fq*4+r;
        float ct = clcs[t], lt = lams[t];
        #pragma unroll
        for (int ni = 0; ni < 4; ni++){
          int j = jj[ni];
          float w = (j < t) ? __expf(ct - clcj[ni])*gj[ni] : ((j == t) ? (1.f - lt) : 0.f);
          pr[mi][ni][r] = f2bf(acc1[mi][ni][r] * w);
        }
      }
    }
    __syncthreads();                     // all MFMA1 reads of Bs complete
    #pragma unroll
    for (int mi = 0; mi < 4; mi++)
      #pragma unroll
      for (int ni = 0; ni < 4; ni++)
        #pragma unroll
        for (int r = 0; r < 4; r++)
          ldsw_write1(Bs, wr*64+mi*16+fq*4+r, wc*64+ni*16+fr, pr[mi][ni][r]);
    __syncthreads();
    // ---- scale state-out by exp(clc_t), then MFMA2: += P . U ----
    #pragma unroll
    for (int mi = 0; mi < 4; mi++)
      #pragma unroll
      for (int ni = 0; ni < 2; ni++)
        #pragma unroll
        for (int r = 0; r < 4; r++)
          accY[mi][ni][r] *= expclcs[wr*64+mi*16+fq*4+r];
    #pragma unroll
    for (int ks = 0; ks < 4; ks++){
      bf16x8 af[4], uj[2];
      #pragma unroll
      for (int mi = 0; mi < 4; mi++) af[mi] = ldsw_read8(Bs, wr*64+mi*16+fr, ks*32+fq*8);
      #pragma unroll
      for (int ni = 0; ni < 2; ni++) uj[ni] = ldsw_read8(Uts, wc*32+ni*16+fr, ks*32+fq*8);
      #pragma unroll
      for (int mi = 0; mi < 4; mi++)
        #pragma unroll
        for (int ni = 0; ni < 2; ni++)
          accY[mi][ni] = __builtin_amdgcn_mfma_f32_16x16x32_bf16(af[mi], uj[ni], accY[mi][ni], 0,0,0);
    }
    // ---- gate + store y ----
    #pragma unroll
    for (int mi = 0; mi < 4; mi++){
      #pragma unroll
      for (int ni = 0; ni < 2; ni++){
        #pragma unroll
        for (int r = 0; r < 4; r++){
          int t = wr*64+mi*16+fq*4+r;
          int p = wc*32+ni*16+fr;
          float xv = bf2f(ldsw_read1(Uts, p, t)) / fmaxf(dts[t], 1e-30f);
          float zv = bf2f(zs[t*64 + p]);
          float sl = zv / (1.f + __expf(-zv));
          float o = (accY[mi][ni][r] + Dh*xv) * sl;
          ybf[(size_t)(base + t)*4096 + h*64 + p] = f2bf(o);
        }
      }
    }
    // ---- MFMA4: state update S = decEnd*S + (wU o U) . B ----
    {
      float decEnd = __expf(clcs[127]);
      #pragma unroll
      for (int mi = 0; mi < 2; mi++)
        #pragma unroll
        for (int ni = 0; ni < 4; ni++)
          #pragma unroll
          for (int r = 0; r < 4; r++)
            accS[mi][ni][r] *= decEnd;
      #pragma unroll
      for (int ks = 0; ks < 4; ks++){
        bf16x8 au[2], bn[4];
        #pragma unroll
        for (int mi = 0; mi < 2; mi++){
          bf16x8 raw = ldsw_read8(Uts, wr*32+mi*16+fr, ks*32+fq*8);
          #pragma unroll
          for (int e = 0; e < 8; e++){
            float f = bf2f((unsigned short)raw[e]) * wUs[ks*32+fq*8+e];
            au[mi][e] = (short)f2bf(f);
          }
        }
        #pragma unroll
        for (int ni = 0; ni < 4; ni++) bn[ni] = ldsw_read8(BTs, wc*64+ni*16+fr, ks*32+fq*8);
        #pragma unroll
        for (int mi = 0; mi < 2; mi++)
          #pragma unroll
          for (int ni = 0; ni < 4; ni++)
            accS[mi][ni] = __builtin_amdgcn_mfma_f32_16x16x32_bf16(au[mi], bn[ni], accS[mi][ni], 0,0,0);
      }
    }
    __syncthreads();
  }
}

// ---------- launch ----------
extern "C" void kernel_launch(void* const* d_in, const int* in_sizes, int n_in,
                              void* d_out, int out_size, void* d_ws, size_t ws_size,
                              hipStream_t stream)
{
  const float* hs    = (const float*)d_in[0];
  const float* w1    = (const float*)d_in[1];
  const float* dtb   = (const float*)d_in[2];
  const float* Bbias = (const float*)d_in[3];
  const float* Cbias = (const float*)d_in[4];
  const float* Bw    = (const float*)d_in[5];
  const float* Cw    = (const float*)d_in[6];
  const float* Dv    = (const float*)d_in[7];
  const float* wo    = (const float*)d_in[8];
  float* out = (float*)d_out;
  char* ws = (char*)d_ws;

  // ws layout (lifetime-overlapped), total 91,619,328 bytes:
  unsigned short* projbf = (unsigned short*)(ws + 0UL);          // 35,651,584
  unsigned short* W1bf   = (unsigned short*)(ws + 35651584UL);   // GEMM1 only
  unsigned short* Wobf   = W1bf;                                  // 16,777,216 (post-GEMM1)
  unsigned short* ybf    = (unsigned short*)(ws + 52428800UL);   // 16,777,216
  unsigned short* hsbf   = (unsigned short*)(ws + 71172096UL);   // GEMM1 only
  unsigned short* cosb   = hsbf;                                  // 8,388,608 (post-GEMM1)
  unsigned short* sinb   = (unsigned short*)(ws + 79560704UL);   // 8,388,608
  float* DTt    = (float*)(ws + 87949312UL);
  float* logdec = (float*)(ws + 88473600UL);
  float* lamt   = (float*)(ws + 88997888UL);
  float* clcb   = (float*)(ws + 89522176UL);
  float* gb     = (float*)(ws + 90046464UL);
  unsigned short* Bb2 = (unsigned short*)(ws + 90570752UL);
  unsigned short* Cb2 = (unsigned short*)(ws + 91095040UL);
  if (ws_size < 91619328UL) return;

  (void)in_sizes; (void)n_in; (void)out_size;

  k_f32_to_bf16<<<17344, 256, 0, stream>>>(w1, W1bf, 17760256L);
  k_f32_to_bf16<<<4096,  256, 0, stream>>>(hs, hsbf, 4194304L);
  k_gemm_bt<true><<<16*68, 256, 0, stream>>>(hsbf, W1bf, projbf, 2048, 8672, 8704, 68);
  k_prep_scalars<<<512, 256, 0, stream>>>(projbf, dtb, DTt, logdec, lamt);
  k_rmsnorm<<<2048, 128, 0, stream>>>(projbf, Bw, Cw, Bb2, Cb2);
  k_chunkscan<<<128, 256, 0, stream>>>(logdec, lamt, clcb, gb);
  k_phase<<<128, 256, 0, stream>>>(projbf, DTt, cosb, sinb);
  k_f32_to_bf16<<<8192, 256, 0, stream>>>(wo, Wobf, 8388608L);
  k_chunk<<<128, 256, 0, stream>>>(projbf, Bb2, Cb2, Bbias, Cbias,
                                   cosb, sinb, DTt, clcb, gb, lamt, Dv, ybf);
  k_gemm_bt<false><<<16*16, 256, 0, stream>>>(ybf, Wobf, out, 4096, 2048, 2048, 16);
}

// Round 3
// 367.676 us; speedup vs baseline: 5.6763x; 1.4583x over previous
//
#include <hip/hip_runtime.h>
#include <hip/hip_bf16.h>
#include <cstdint>
#include <cstddef>

#define DEVINL __device__ __forceinline__

typedef __attribute__((ext_vector_type(8))) short bf16x8;
typedef __attribute__((ext_vector_type(4))) float f32x4;

// ---------- helpers ----------
DEVINL float bf2f(unsigned short u){
  union { unsigned u32; float f; } cv; cv.u32 = ((unsigned)u) << 16; return cv.f;
}
DEVINL unsigned short f2bf(float f){
  union { float f; unsigned u32; } cv; cv.f = f;
  unsigned u = cv.u32;
  return (unsigned short)((u + 0x7FFFu + ((u >> 16) & 1u)) >> 16);  // RNE
}
DEVINL float softplusf(float x){ return x > 20.f ? x : log1pf(expf(x)); }

DEVINL void g2l16(const void* gptr, void* ldsptr){
  __builtin_amdgcn_global_load_lds(
      (const __attribute__((address_space(1))) unsigned int*)gptr,
      (__attribute__((address_space(3))) unsigned int*)(uintptr_t)ldsptr,
      16, 0, 0);
}

// swizzled LDS access; all tiles have 256-byte rows (128 bf16 cols)
DEVINL int swzb(int row, int col){ return row*256 + ((col*2) ^ ((row&7)<<4)); }
DEVINL void ldsw_write8(unsigned short* b, int row, int col, bf16x8 v){
  *(bf16x8*)((char*)b + swzb(row,col)) = v;
}
DEVINL bf16x8 ldsw_read8(const unsigned short* b, int row, int col){
  return *(const bf16x8*)((const char*)b + swzb(row,col));
}
DEVINL void ldsw_write1(unsigned short* b, int row, int col, unsigned short v){
  *(unsigned short*)((char*)b + swzb(row,col)) = v;
}
DEVINL unsigned short ldsw_read1(const unsigned short* b, int row, int col){
  return *(const unsigned short*)((const char*)b + swzb(row,col));
}

// ---------- f32 -> bf16 conversion ----------
__global__ __launch_bounds__(256) void k_f32_to_bf16(
    const float* __restrict__ in, unsigned short* __restrict__ out, long n)
{
  long i = ((long)blockIdx.x * 256 + threadIdx.x) * 4;
  if (i + 3 < n){
    float4 v = *(const float4*)(in + i);
    unsigned long long pk =
        (unsigned long long)f2bf(v.x)
      | ((unsigned long long)f2bf(v.y) << 16)
      | ((unsigned long long)f2bf(v.z) << 32)
      | ((unsigned long long)f2bf(v.w) << 48);
    *(unsigned long long*)(out + i) = pk;
  }
}

// ---------- bf16 GEMM, both operands K-major, C = A * Bt^T ----------
template<bool OUT_BF16>
__global__ __launch_bounds__(256) void k_gemm_bt(
    const unsigned short* __restrict__ A,
    const unsigned short* __restrict__ Bt,
    void* __restrict__ Cout,
    int K, int Nrows, int Npad, int tiles_n)
{
  __shared__ unsigned short Asub[128*32];
  __shared__ unsigned short Bsub[128*32];
  const int tid = threadIdx.x;
  const int rt = blockIdx.x / tiles_n, ct = blockIdx.x % tiles_n;
  const int lane = tid & 63, wave = tid >> 6;
  const int wr = wave >> 1, wc = wave & 1;

  const int sr = tid >> 2;
  const int sc = (tid & 3) * 8;
  const size_t a_r0 = (size_t)(rt*128 + sr) * K + sc;
  const size_t a_r1 = a_r0 + (size_t)64 * K;
  int b0 = ct*128 + sr;      if (b0 > Nrows-1) b0 = Nrows-1;
  int b1 = ct*128 + 64 + sr; if (b1 > Nrows-1) b1 = Nrows-1;
  const size_t b_r0 = (size_t)b0 * K + sc;
  const size_t b_r1 = (size_t)b1 * K + sc;

  char* aL0 = (char*)Asub + tid*16;
  char* aL1 = (char*)Asub + 4096 + tid*16;
  char* bL0 = (char*)Bsub + tid*16;
  char* bL1 = (char*)Bsub + 4096 + tid*16;

  f32x4 acc[4][4] = {};
  const int fr = lane & 15;
  const int fk = (lane >> 4) * 8;

  for (int k0 = 0; k0 < K; k0 += 32){
    g2l16(A  + a_r0 + k0, aL0);
    g2l16(A  + a_r1 + k0, aL1);
    g2l16(Bt + b_r0 + k0, bL0);
    g2l16(Bt + b_r1 + k0, bL1);
    asm volatile("s_waitcnt vmcnt(0)" ::: "memory");
    __syncthreads();

    bf16x8 af[4], bfr[4];
    #pragma unroll
    for (int i = 0; i < 4; i++){
      af[i]  = *(const bf16x8*)&Asub[(wr*64 + i*16 + fr)*32 + fk];
      bfr[i] = *(const bf16x8*)&Bsub[(wc*64 + i*16 + fr)*32 + fk];
    }
    #pragma unroll
    for (int mi = 0; mi < 4; mi++)
      #pragma unroll
      for (int ni = 0; ni < 4; ni++)
        acc[mi][ni] = __builtin_amdgcn_mfma_f32_16x16x32_bf16(af[mi], bfr[ni], acc[mi][ni], 0, 0, 0);
    __syncthreads();
  }

  const int er = (lane >> 4) * 4;
  const int ec = lane & 15;
  #pragma unroll
  for (int mi = 0; mi < 4; mi++){
    #pragma unroll
    for (int ni = 0; ni < 4; ni++){
      const int row = rt*128 + wr*64 + mi*16 + er;
      const int col = ct*128 + wc*64 + ni*16 + ec;
      #pragma unroll
      for (int r = 0; r < 4; r++){
        if (OUT_BF16)
          ((unsigned short*)Cout)[(size_t)(row+r)*Npad + col] = f2bf(acc[mi][ni][r]);
        else
          ((float*)Cout)[(size_t)(row+r)*Npad + col] = acc[mi][ni][r];
      }
    }
  }
}

// ---------- per-(b,l,h) scalars -> [b][h][l] layouts ----------
__global__ __launch_bounds__(256) void k_prep_scalars(
    const unsigned short* __restrict__ proj, const float* __restrict__ dt_bias,
    float* __restrict__ DTt, float* __restrict__ logdec, float* __restrict__ lamt)
{
  int idx = blockIdx.x*256 + threadIdx.x;   // (b*1024+l)*64 + h
  int h = idx & 63, row = idx >> 6;
  int b = row >> 10, l = row & 1023;
  size_t base = (size_t)row * 8704;
  float dd_dt = bf2f(proj[base + 8448 + h]);
  float dd_A  = bf2f(proj[base + 8512 + h]);
  float trap  = bf2f(proj[base + 8576 + h]);
  float DT = softplusf(dd_dt + dt_bias[h]);
  float A  = -fmaxf(softplusf(dd_A), 1e-4f);
  size_t o = ((size_t)(b*64 + h))*1024 + l;
  DTt[o]    = DT;
  logdec[o] = A * DT;
  lamt[o]   = 1.f / (1.f + expf(-trap));
}

// ---------- rmsnorm of Braw/Craw rows (N=128) -> bf16 ----------
__global__ __launch_bounds__(128) void k_rmsnorm(
    const unsigned short* __restrict__ proj, const float* __restrict__ Bw,
    const float* __restrict__ Cw, unsigned short* __restrict__ Bb2,
    unsigned short* __restrict__ Cb2)
{
  int row = blockIdx.x, n = threadIdx.x;
  size_t base = (size_t)row * 8704;
  float bv = bf2f(proj[base + 8192 + n]);
  float cv = bf2f(proj[base + 8320 + n]);
  float sb = bv*bv, sc = cv*cv;
  #pragma unroll
  for (int m = 1; m < 64; m <<= 1){ sb += __shfl_xor(sb, m, 64); sc += __shfl_xor(sc, m, 64); }
  __shared__ float red[4];
  if ((n & 63) == 0){ red[(n>>6)*2] = sb; red[(n>>6)*2+1] = sc; }
  __syncthreads();
  sb = red[0] + red[2];
  sc = red[1] + red[3];
  float rb = rsqrtf(sb*(1.f/128.f) + 1e-5f);
  float rc = rsqrtf(sc*(1.f/128.f) + 1e-5f);
  Bb2[row*128 + n] = f2bf(bv*rb*Bw[n]);
  Cb2[row*128 + n] = f2bf(cv*rc*Cw[n]);
}

// ---------- per-chunk(128) inclusive cumsum of logdec + g = 1-lam+lam_next ----------
__global__ __launch_bounds__(256) void k_chunkscan(
    const float* __restrict__ logdec, const float* __restrict__ lamt,
    float* __restrict__ clcb, float* __restrict__ gb)
{
  int bh = blockIdx.x;
  size_t base = (size_t)bh * 1024;
  int tid = threadIdx.x;
  int e0 = tid * 4;
  float v0 = logdec[base+e0], v1 = logdec[base+e0+1], v2 = logdec[base+e0+2], v3 = logdec[base+e0+3];
  float p0 = v0, p1 = p0+v1, p2 = p1+v2, p3 = p2+v3;
  float tot = p3;
  int sub = tid & 31;
  float incl = tot;
  #pragma unroll
  for (int off = 1; off < 32; off <<= 1){
    float u = __shfl_up(incl, off, 32);
    if (sub >= off) incl += u;
  }
  float excl = incl - tot;
  clcb[base+e0]   = excl + p0;
  clcb[base+e0+1] = excl + p1;
  clcb[base+e0+2] = excl + p2;
  clcb[base+e0+3] = excl + p3;
  #pragma unroll
  for (int i = 0; i < 4; i++){
    int l = e0 + i;
    int ln = (l == 1023) ? 1023 : l + 1;
    gb[base+l] = 1.f - lamt[base+l] + lamt[base+ln];
  }
}

// ---------- phase cumsum + cos/sin tables; block per (b,h), 256 thr = 32 na x 8 chunks ----------
__global__ __launch_bounds__(256) void k_phase(
    const unsigned short* __restrict__ proj, const float* __restrict__ DTt,
    unsigned short* __restrict__ cosb, unsigned short* __restrict__ sinb)
{
  int bh = blockIdx.x, b = bh >> 6, h = bh & 63;
  int na = threadIdx.x & 31, c = threadIdx.x >> 5;
  __shared__ float part[8][32];
  const float* dtr = DTt + (size_t)bh * 1024;
  float s = 0.f;
  for (int i = 0; i < 128; i++){
    int l = c*128 + i; int row = b*1024 + l;
    float ang = bf2f(proj[(size_t)row*8704 + 8640 + na]);
    s = fmaf(ang, dtr[l], s);
  }
  part[c][na] = s;
  __syncthreads();
  float off = 0.f;
  for (int cc = 0; cc < c; cc++) off += part[cc][na];
  float ph = off;
  for (int i = 0; i < 128; i++){
    int l = c*128 + i; int row = b*1024 + l;
    float ang = bf2f(proj[(size_t)row*8704 + 8640 + na]);
    ph = fmaf(ang, dtr[l], ph);
    float sn, cs;
    __sincosf(ph, &sn, &cs);
    size_t o = ((size_t)row*64 + h)*32 + na;
    cosb[o] = f2bf(cs); sinb[o] = f2bf(sn);
  }
}

// ---------- pass A: intra-chunk y + chunk state increment G ----------
// block = (bh, c): y_intra[t][p] = sum_j v_{t,j} u_j[p] (B_j.C_t)  (+ D*x, ungated)
// G[p][n] = sum_j exp(clcEnd-clc_j) g_j u_j[p] B_j[n]
__global__ __launch_bounds__(256, 1) void k_intra(
    const unsigned short* __restrict__ proj,
    const unsigned short* __restrict__ Bb2, const unsigned short* __restrict__ Cb2,
    const float* __restrict__ Bbias, const float* __restrict__ Cbias,
    const unsigned short* __restrict__ cosb, const unsigned short* __restrict__ sinb,
    const float* __restrict__ DTt, const float* __restrict__ clcb,
    const float* __restrict__ gb, const float* __restrict__ lamt,
    const float* __restrict__ Dv, unsigned short* __restrict__ ybf,
    unsigned short* __restrict__ Gbuf)
{
  const int c = blockIdx.x & 7, bh = blockIdx.x >> 3;
  const int b = bh >> 6, h = bh & 63;
  const int tid = threadIdx.x, lane = tid & 63, wave = tid >> 6;
  const int wr = wave >> 1, wc = wave & 1;
  const int fr = lane & 15, fq = lane >> 4;

  __shared__ __align__(16) unsigned short Cs[128*128];
  __shared__ __align__(16) unsigned short Bs[128*128];   // aliased as P after barrier
  __shared__ __align__(16) unsigned short BTs[128*128];
  __shared__ __align__(16) unsigned short Uts[64*128];   // U^T: [p][j]
  __shared__ float clcs[128], lams[128], gs[128], wUs[128], dts[128];
  __shared__ float biasB[128], biasC[128];

  const int base = b*1024 + c*128;
  const size_t shbase = (size_t)bh * 1024;
  const float Dh = Dv[h];

  // phase 0: scalars
  if (tid < 128){
    int l = c*128 + tid;
    clcs[tid] = clcb[shbase + l];
    dts[tid]  = DTt[shbase + l];
    lams[tid] = lamt[shbase + l];
    gs[tid]   = gb[shbase + l];
    biasB[tid] = Bbias[h*128 + tid];
  } else {
    biasC[tid-128] = Cbias[h*128 + tid-128];
  }
  __syncthreads();
  if (tid < 128) wUs[tid] = __expf(clcs[127] - clcs[tid]) * gs[tid];

  // phase 1: stage C/B (bias+rope), B^T, U^T
  {
    const int t = tid >> 1, half = tid & 1;
    const int grow = base + t;
    const size_t roff = (size_t)grow*128 + half*64;
    if (half == 0){
      bf16x8 cc[4], sv[4];
      #pragma unroll
      for (int i = 0; i < 4; i++){
        cc[i] = *(const bf16x8*)(cosb + ((size_t)grow*64 + h)*32 + i*8);
        sv[i] = *(const bf16x8*)(sinb + ((size_t)grow*64 + h)*32 + i*8);
      }
      #pragma unroll
      for (int i = 0; i < 4; i++){
        bf16x8 vlo = *(const bf16x8*)(Cb2 + roff + i*8);
        bf16x8 vhi = *(const bf16x8*)(Cb2 + roff + 32 + i*8);
        bf16x8 olo, ohi;
        #pragma unroll
        for (int e = 0; e < 8; e++){
          float a = bf2f((unsigned short)vlo[e]) + biasC[i*8+e];
          float d = bf2f((unsigned short)vhi[e]) + biasC[32+i*8+e];
          float cf = bf2f((unsigned short)cc[i][e]);
          float sf = bf2f((unsigned short)sv[i][e]);
          olo[e] = (short)f2bf(a*cf - d*sf);
          ohi[e] = (short)f2bf(a*sf + d*cf);
        }
        ldsw_write8(Cs, t, i*8, olo);
        ldsw_write8(Cs, t, 32 + i*8, ohi);
      }
      #pragma unroll
      for (int i = 0; i < 4; i++){
        bf16x8 vlo = *(const bf16x8*)(Bb2 + roff + i*8);
        bf16x8 vhi = *(const bf16x8*)(Bb2 + roff + 32 + i*8);
        bf16x8 olo, ohi;
        #pragma unroll
        for (int e = 0; e < 8; e++){
          float a = bf2f((unsigned short)vlo[e]) + biasB[i*8+e];
          float d = bf2f((unsigned short)vhi[e]) + biasB[32+i*8+e];
          float cf = bf2f((unsigned short)cc[i][e]);
          float sf = bf2f((unsigned short)sv[i][e]);
          olo[e] = (short)f2bf(a*cf - d*sf);
          ohi[e] = (short)f2bf(a*sf + d*cf);
        }
        ldsw_write8(Bs, t, i*8, olo);
        ldsw_write8(Bs, t, 32 + i*8, ohi);
        #pragma unroll
        for (int e = 0; e < 8; e++){
          ldsw_write1(BTs, i*8+e, t, (unsigned short)olo[e]);
          ldsw_write1(BTs, 32+i*8+e, t, (unsigned short)ohi[e]);
        }
      }
    } else {
      #pragma unroll
      for (int i = 0; i < 8; i++){
        bf16x8 v = *(const bf16x8*)(Cb2 + roff + i*8);
        bf16x8 o;
        #pragma unroll
        for (int e = 0; e < 8; e++) o[e] = (short)f2bf(bf2f((unsigned short)v[e]) + biasC[64+i*8+e]);
        ldsw_write8(Cs, t, 64 + i*8, o);
      }
      #pragma unroll
      for (int i = 0; i < 8; i++){
        bf16x8 v = *(const bf16x8*)(Bb2 + roff + i*8);
        bf16x8 o;
        #pragma unroll
        for (int e = 0; e < 8; e++) o[e] = (short)f2bf(bf2f((unsigned short)v[e]) + biasB[64+i*8+e]);
        ldsw_write8(Bs, t, 64 + i*8, o);
        #pragma unroll
        for (int e = 0; e < 8; e++) ldsw_write1(BTs, 64+i*8+e, t, (unsigned short)o[e]);
      }
    }
  }
  {
    const int p = tid & 63, jg = tid >> 6;
    #pragma unroll 4
    for (int i = 0; i < 32; i++){
      int j = jg*32 + i;
      size_t pb = (size_t)(base + j) * 8704;
      float x  = bf2f(proj[pb + 4096 + h*64 + p]);
      ldsw_write1(Uts, p, j, f2bf(x * dts[j]));
    }
  }
  __syncthreads();

  // MFMA1: scores[t][j] = C . B^T
  f32x4 acc1[4][4];
  #pragma unroll
  for (int mi = 0; mi < 4; mi++)
    #pragma unroll
    for (int ni = 0; ni < 4; ni++)
      acc1[mi][ni] = (f32x4){0.f,0.f,0.f,0.f};
  #pragma unroll
  for (int ks = 0; ks < 4; ks++){
    bf16x8 af[4], bj[4];
    #pragma unroll
    for (int mi = 0; mi < 4; mi++) af[mi] = ldsw_read8(Cs, wr*64+mi*16+fr, ks*32+fq*8);
    #pragma unroll
    for (int ni = 0; ni < 4; ni++) bj[ni] = ldsw_read8(Bs, wc*64+ni*16+fr, ks*32+fq*8);
    #pragma unroll
    for (int mi = 0; mi < 4; mi++)
      #pragma unroll
      for (int ni = 0; ni < 4; ni++)
        acc1[mi][ni] = __builtin_amdgcn_mfma_f32_16x16x32_bf16(af[mi], bj[ni], acc1[mi][ni], 0,0,0);
  }
  // weight epilogue: P = W o scores
  unsigned short pr[4][4][4];
  int jj[4]; float clcj[4], gj[4];
  #pragma unroll
  for (int ni = 0; ni < 4; ni++){ jj[ni] = wc*64+ni*16+fr; clcj[ni] = clcs[jj[ni]]; gj[ni] = gs[jj[ni]]; }
  #pragma unroll
  for (int mi = 0; mi < 4; mi++){
    #pragma unroll
    for (int r = 0; r < 4; r++){
      int t = wr*64+mi*16+fq*4+r;
      float ct = clcs[t], lt = lams[t];
      #pragma unroll
      for (int ni = 0; ni < 4; ni++){
        int j = jj[ni];
        float w = (j < t) ? __expf(ct - clcj[ni])*gj[ni] : ((j == t) ? (1.f - lt) : 0.f);
        pr[mi][ni][r] = f2bf(acc1[mi][ni][r] * w);
      }
    }
  }
  __syncthreads();                     // all MFMA1 reads of Bs complete
  #pragma unroll
  for (int mi = 0; mi < 4; mi++)
    #pragma unroll
    for (int ni = 0; ni < 4; ni++)
      #pragma unroll
      for (int r = 0; r < 4; r++)
        ldsw_write1(Bs, wr*64+mi*16+fq*4+r, wc*64+ni*16+fr, pr[mi][ni][r]);
  __syncthreads();

  // MFMA2: y_intra[t][p] = P . U
  f32x4 acc2[4][2];
  #pragma unroll
  for (int mi = 0; mi < 4; mi++)
    #pragma unroll
    for (int ni = 0; ni < 2; ni++)
      acc2[mi][ni] = (f32x4){0.f,0.f,0.f,0.f};
  #pragma unroll
  for (int ks = 0; ks < 4; ks++){
    bf16x8 af[4], uj[2];
    #pragma unroll
    for (int mi = 0; mi < 4; mi++) af[mi] = ldsw_read8(Bs, wr*64+mi*16+fr, ks*32+fq*8);
    #pragma unroll
    for (int ni = 0; ni < 2; ni++) uj[ni] = ldsw_read8(Uts, wc*32+ni*16+fr, ks*32+fq*8);
    #pragma unroll
    for (int mi = 0; mi < 4; mi++)
      #pragma unroll
      for (int ni = 0; ni < 2; ni++)
        acc2[mi][ni] = __builtin_amdgcn_mfma_f32_16x16x32_bf16(af[mi], uj[ni], acc2[mi][ni], 0,0,0);
  }
  // MFMA4: G[p][n] = (wU o U) . B   (B-operand = BTs)
  f32x4 accS[2][4];
  #pragma unroll
  for (int mi = 0; mi < 2; mi++)
    #pragma unroll
    for (int ni = 0; ni < 4; ni++)
      accS[mi][ni] = (f32x4){0.f,0.f,0.f,0.f};
  #pragma unroll
  for (int ks = 0; ks < 4; ks++){
    bf16x8 au[2], bn[4];
    #pragma unroll
    for (int mi = 0; mi < 2; mi++){
      bf16x8 raw = ldsw_read8(Uts, wr*32+mi*16+fr, ks*32+fq*8);
      #pragma unroll
      for (int e = 0; e < 8; e++){
        float f = bf2f((unsigned short)raw[e]) * wUs[ks*32+fq*8+e];
        au[mi][e] = (short)f2bf(f);
      }
    }
    #pragma unroll
    for (int ni = 0; ni < 4; ni++) bn[ni] = ldsw_read8(BTs, wc*64+ni*16+fr, ks*32+fq*8);
    #pragma unroll
    for (int mi = 0; mi < 2; mi++)
      #pragma unroll
      for (int ni = 0; ni < 4; ni++)
        accS[mi][ni] = __builtin_amdgcn_mfma_f32_16x16x32_bf16(au[mi], bn[ni], accS[mi][ni], 0,0,0);
  }

  // stores: y_intra + D*x (ungated) and G
  #pragma unroll
  for (int mi = 0; mi < 4; mi++){
    #pragma unroll
    for (int ni = 0; ni < 2; ni++){
      #pragma unroll
      for (int r = 0; r < 4; r++){
        int t = wr*64+mi*16+fq*4+r;
        int p = wc*32+ni*16+fr;
        float xv = bf2f(ldsw_read1(Uts, p, t)) / fmaxf(dts[t], 1e-30f);
        float o = acc2[mi][ni][r] + Dh*xv;
        ybf[(size_t)(base + t)*4096 + h*64 + p] = f2bf(o);
      }
    }
  }
  #pragma unroll
  for (int mi = 0; mi < 2; mi++)
    #pragma unroll
    for (int ni = 0; ni < 4; ni++)
      #pragma unroll
      for (int r = 0; r < 4; r++){
        int p = wr*32+mi*16+fq*4+r;
        int n = wc*64+ni*16+fr;
        Gbuf[(size_t)blockIdx.x*8192 + p*128 + n] = f2bf(accS[mi][ni][r]);
      }
}

// ---------- pass B: scan over 8 chunks; Gbuf[c] <- S_prev(c), S = decEnd*S + G ----------
__global__ __launch_bounds__(256) void k_scanstate(
    const float* __restrict__ clcb, unsigned short* __restrict__ Gbuf)
{
  const int bh = blockIdx.x, tid = threadIdx.x;
  float S[32];
  #pragma unroll
  for (int i = 0; i < 32; i++) S[i] = 0.f;
  const size_t gbase = (size_t)bh*65536 + (size_t)tid*32;
  for (int c = 0; c < 8; c++){
    float decEnd = __expf(clcb[(size_t)bh*1024 + c*128 + 127]);
    unsigned short* p = Gbuf + gbase + (size_t)c*8192;
    bf16x8 g[4], s[4];
    #pragma unroll
    for (int i = 0; i < 4; i++) g[i] = *(const bf16x8*)(p + i*8);
    #pragma unroll
    for (int i = 0; i < 4; i++)
      #pragma unroll
      for (int e = 0; e < 8; e++) s[i][e] = (short)f2bf(S[i*8+e]);
    #pragma unroll
    for (int i = 0; i < 4; i++) *(bf16x8*)(p + i*8) = s[i];
    #pragma unroll
    for (int i = 0; i < 4; i++)
      #pragma unroll
      for (int e = 0; e < 8; e++)
        S[i*8+e] = decEnd*S[i*8+e] + bf2f((unsigned short)g[i][e]);
  }
}

// ---------- pass C: y = (y_intra + exp(clc_t) * C_t . S_prev^T) * silu(z) ----------
__global__ __launch_bounds__(256) void k_inter(
    const unsigned short* __restrict__ proj,
    const unsigned short* __restrict__ Cb2, const float* __restrict__ Cbias,
    const unsigned short* __restrict__ cosb, const unsigned short* __restrict__ sinb,
    const float* __restrict__ clcb, const unsigned short* __restrict__ Sprev,
    unsigned short* __restrict__ ybf)
{
  const int c = blockIdx.x & 7, bh = blockIdx.x >> 3;
  const int b = bh >> 6, h = bh & 63;
  const int tid = threadIdx.x, lane = tid & 63, wave = tid >> 6;
  const int wr = wave >> 1, wc = wave & 1;
  const int fr = lane & 15, fq = lane >> 4;

  __shared__ __align__(16) unsigned short Cs[128*128];
  __shared__ __align__(16) unsigned short Ss[64*128];
  __shared__ float expclcs[128], biasC[128];

  const int base = b*1024 + c*128;

  if (tid < 128){
    expclcs[tid] = __expf(clcb[(size_t)bh*1024 + c*128 + tid]);
    biasC[tid] = Cbias[h*128 + tid];
  }
  __syncthreads();

  // stage C (bias+rope)
  {
    const int t = tid >> 1, half = tid & 1;
    const int grow = base + t;
    const size_t roff = (size_t)grow*128 + half*64;
    if (half == 0){
      bf16x8 cc[4], sv[4];
      #pragma unroll
      for (int i = 0; i < 4; i++){
        cc[i] = *(const bf16x8*)(cosb + ((size_t)grow*64 + h)*32 + i*8);
        sv[i] = *(const bf16x8*)(sinb + ((size_t)grow*64 + h)*32 + i*8);
      }
      #pragma unroll
      for (int i = 0; i < 4; i++){
        bf16x8 vlo = *(const bf16x8*)(Cb2 + roff + i*8);
        bf16x8 vhi = *(const bf16x8*)(Cb2 + roff + 32 + i*8);
        bf16x8 olo, ohi;
        #pragma unroll
        for (int e = 0; e < 8; e++){
          float a = bf2f((unsigned short)vlo[e]) + biasC[i*8+e];
          float d = bf2f((unsigned short)vhi[e]) + biasC[32+i*8+e];
          float cf = bf2f((unsigned short)cc[i][e]);
          float sf = bf2f((unsigned short)sv[i][e]);
          olo[e] = (short)f2bf(a*cf - d*sf);
          ohi[e] = (short)f2bf(a*sf + d*cf);
        }
        ldsw_write8(Cs, t, i*8, olo);
        ldsw_write8(Cs, t, 32 + i*8, ohi);
      }
    } else {
      #pragma unroll
      for (int i = 0; i < 8; i++){
        bf16x8 v = *(const bf16x8*)(Cb2 + roff + i*8);
        bf16x8 o;
        #pragma unroll
        for (int e = 0; e < 8; e++) o[e] = (short)f2bf(bf2f((unsigned short)v[e]) + biasC[64+i*8+e]);
        ldsw_write8(Cs, t, 64 + i*8, o);
      }
    }
  }
  // stage S_prev (reg -> swizzled LDS)
  {
    const unsigned short* src = Sprev + (size_t)blockIdx.x*8192 + (size_t)tid*32;
    #pragma unroll
    for (int i = 0; i < 4; i++){
      bf16x8 v = *(const bf16x8*)(src + i*8);
      int f = tid*32 + i*8;
      ldsw_write8(Ss, f >> 7, f & 127, v);
    }
  }
  __syncthreads();

  // MFMA: Yinter[t][p] = C . S_prev^T
  f32x4 acc[4][2];
  #pragma unroll
  for (int mi = 0; mi < 4; mi++)
    #pragma unroll
    for (int ni = 0; ni < 2; ni++)
      acc[mi][ni] = (f32x4){0.f,0.f,0.f,0.f};
  #pragma unroll
  for (int ks = 0; ks < 4; ks++){
    bf16x8 af[4], sj[2];
    #pragma unroll
    for (int mi = 0; mi < 4; mi++) af[mi] = ldsw_read8(Cs, wr*64+mi*16+fr, ks*32+fq*8);
    #pragma unroll
    for (int ni = 0; ni < 2; ni++) sj[ni] = ldsw_read8(Ss, wc*32+ni*16+fr, ks*32+fq*8);
    #pragma unroll
    for (int mi = 0; mi < 4; mi++)
      #pragma unroll
      for (int ni = 0; ni < 2; ni++)
        acc[mi][ni] = __builtin_amdgcn_mfma_f32_16x16x32_bf16(af[mi], sj[ni], acc[mi][ni], 0,0,0);
  }

  // epilogue: y = (y_intra + expclc*Yinter) * silu(z)
  #pragma unroll
  for (int mi = 0; mi < 4; mi++){
    #pragma unroll
    for (int ni = 0; ni < 2; ni++){
      #pragma unroll
      for (int r = 0; r < 4; r++){
        int t = wr*64+mi*16+fq*4+r;
        int p = wc*32+ni*16+fr;
        size_t yoff = (size_t)(base + t)*4096 + h*64 + p;
        float y = bf2f(ybf[yoff]) + expclcs[t]*acc[mi][ni][r];
        float zv = bf2f(proj[(size_t)(base + t)*8704 + h*64 + p]);
        float sl = zv / (1.f + __expf(-zv));
        ybf[yoff] = f2bf(y * sl);
      }
    }
  }
}

// ---------- launch ----------
extern "C" void kernel_launch(void* const* d_in, const int* in_sizes, int n_in,
                              void* d_out, int out_size, void* d_ws, size_t ws_size,
                              hipStream_t stream)
{
  const float* hs    = (const float*)d_in[0];
  const float* w1    = (const float*)d_in[1];
  const float* dtb   = (const float*)d_in[2];
  const float* Bbias = (const float*)d_in[3];
  const float* Cbias = (const float*)d_in[4];
  const float* Bw    = (const float*)d_in[5];
  const float* Cw    = (const float*)d_in[6];
  const float* Dv    = (const float*)d_in[7];
  const float* wo    = (const float*)d_in[8];
  float* out = (float*)d_out;
  char* ws = (char*)d_ws;

  // ws layout (lifetime-overlapped), total 91,619,328 bytes:
  //  [0, 35.65M)        projbf (2048x8704 bf16), live GEMM1 -> k_inter
  //  [35.65M, 71.17M)   W1bf during GEMM1; then Gbuf(16.78M)@35.65M during passes A-C;
  //                     then Wobf(16.78M)@35.65M for GEMM2.  ybf(16.78M)@52.43M.
  //  [71.17M, 79.56M)   hsbf during GEMM1; then cosb
  //  [79.56M, 87.95M)   sinb
  //  [87.95M, 91.62M)   DTt/logdec/lamt/clcb/gb (f32) + Bb2/Cb2 (bf16)
  unsigned short* projbf = (unsigned short*)(ws + 0UL);
  unsigned short* W1bf   = (unsigned short*)(ws + 35651584UL);
  unsigned short* Gbuf   = W1bf;                                  // post-GEMM1
  unsigned short* Wobf   = W1bf;                                  // post-k_inter
  unsigned short* ybf    = (unsigned short*)(ws + 52428800UL);
  unsigned short* hsbf   = (unsigned short*)(ws + 71172096UL);
  unsigned short* cosb   = hsbf;                                  // post-GEMM1
  unsigned short* sinb   = (unsigned short*)(ws + 79560704UL);
  float* DTt    = (float*)(ws + 87949312UL);
  float* logdec = (float*)(ws + 88473600UL);
  float* lamt   = (float*)(ws + 88997888UL);
  float* clcb   = (float*)(ws + 89522176UL);
  float* gb     = (float*)(ws + 90046464UL);
  unsigned short* Bb2 = (unsigned short*)(ws + 90570752UL);
  unsigned short* Cb2 = (unsigned short*)(ws + 91095040UL);
  if (ws_size < 91619328UL) return;

  (void)in_sizes; (void)n_in; (void)out_size;

  k_f32_to_bf16<<<17344, 256, 0, stream>>>(w1, W1bf, 17760256L);
  k_f32_to_bf16<<<4096,  256, 0, stream>>>(hs, hsbf, 4194304L);
  k_gemm_bt<true><<<16*68, 256, 0, stream>>>(hsbf, W1bf, projbf, 2048, 8672, 8704, 68);
  k_prep_scalars<<<512, 256, 0, stream>>>(projbf, dtb, DTt, logdec, lamt);
  k_rmsnorm<<<2048, 128, 0, stream>>>(projbf, Bw, Cw, Bb2, Cb2);
  k_chunkscan<<<128, 256, 0, stream>>>(logdec, lamt, clcb, gb);
  k_phase<<<128, 256, 0, stream>>>(projbf, DTt, cosb, sinb);
  k_intra<<<1024, 256, 0, stream>>>(projbf, Bb2, Cb2, Bbias, Cbias,
                                    cosb, sinb, DTt, clcb, gb, lamt, Dv, ybf, Gbuf);
  k_scanstate<<<128, 256, 0, stream>>>(clcb, Gbuf);
  k_inter<<<1024, 256, 0, stream>>>(projbf, Cb2, Cbias, cosb, sinb, clcb, Gbuf, ybf);
  k_f32_to_bf16<<<8192, 256, 0, stream>>>(wo, Wobf, 8388608L);
  k_gemm_bt<false><<<16*16, 256, 0, stream>>>(ybf, Wobf, out, 4096, 2048, 2048, 16);
}

// Round 4
// 341.311 us; speedup vs baseline: 6.1148x; 1.0772x over previous
//
#include <hip/hip_runtime.h>
#include <hip/hip_bf16.h>
#include <cstdint>
#include <cstddef>

#define DEVINL __device__ __forceinline__

typedef __attribute__((ext_vector_type(8))) short bf16x8;
typedef __attribute__((ext_vector_type(4))) float f32x4;

// ---------- helpers ----------
DEVINL float bf2f(unsigned short u){
  union { unsigned u32; float f; } cv; cv.u32 = ((unsigned)u) << 16; return cv.f;
}
DEVINL unsigned short f2bf(float f){
  union { float f; unsigned u32; } cv; cv.f = f;
  unsigned u = cv.u32;
  return (unsigned short)((u + 0x7FFFu + ((u >> 16) & 1u)) >> 16);  // RNE
}
DEVINL float softplusf(float x){ return x > 20.f ? x : log1pf(expf(x)); }

DEVINL void g2l16(const void* gptr, void* ldsptr){
  __builtin_amdgcn_global_load_lds(
      (const __attribute__((address_space(1))) unsigned int*)gptr,
      (__attribute__((address_space(3))) unsigned int*)(uintptr_t)ldsptr,
      16, 0, 0);
}

// swizzled LDS access for 256-byte-row tiles (128 bf16 cols)
DEVINL int swzb(int row, int col){ return row*256 + ((col*2) ^ ((row&7)<<4)); }
DEVINL void ldsw_write8(unsigned short* b, int row, int col, bf16x8 v){
  *(bf16x8*)((char*)b + swzb(row,col)) = v;
}
DEVINL bf16x8 ldsw_read8(const unsigned short* b, int row, int col){
  return *(const bf16x8*)((const char*)b + swzb(row,col));
}
DEVINL void ldsw_write1(unsigned short* b, int row, int col, unsigned short v){
  *(unsigned short*)((char*)b + swzb(row,col)) = v;
}
DEVINL unsigned short ldsw_read1(const unsigned short* b, int row, int col){
  return *(const unsigned short*)((const char*)b + swzb(row,col));
}

// ---------- f32 -> bf16 conversion ----------
__global__ __launch_bounds__(256) void k_f32_to_bf16(
    const float* __restrict__ in, unsigned short* __restrict__ out, long n)
{
  long i = ((long)blockIdx.x * 256 + threadIdx.x) * 4;
  if (i + 3 < n){
    float4 v = *(const float4*)(in + i);
    unsigned long long pk =
        (unsigned long long)f2bf(v.x)
      | ((unsigned long long)f2bf(v.y) << 16)
      | ((unsigned long long)f2bf(v.z) << 32)
      | ((unsigned long long)f2bf(v.w) << 48);
    *(unsigned long long*)(out + i) = pk;
  }
}

// ---------- bf16 GEMM, both operands K-major, C = A * Bt^T ----------
// 128x128 tile, BK=64, swizzled 16KB LDS tiles (slot ^= row&7), XCD-swizzled grid.
template<bool OUT_BF16>
__global__ __launch_bounds__(256) void k_gemm_bt(
    const unsigned short* __restrict__ A,
    const unsigned short* __restrict__ Bt,
    void* __restrict__ Cout,
    int K, int Nrows, int Npad, int tiles_n)
{
  __shared__ unsigned short Asub[128*64];
  __shared__ unsigned short Bsub[128*64];
  const int tid = threadIdx.x;
  // bijective XCD swizzle (gridDim.x % 8 == 0 for both gemms)
  const int nwg = gridDim.x;
  const int wg = ((nwg & 7) == 0) ? (int)((blockIdx.x & 7) * (nwg >> 3) + (blockIdx.x >> 3))
                                  : (int)blockIdx.x;
  const int rt = wg / tiles_n, ct = wg % tiles_n;
  const int lane = tid & 63, wave = tid >> 6;
  const int wr = wave >> 1, wc = wave & 1;
  const int fr = lane & 15;
  const int fq = lane >> 4;

  // staging map: pos = i*256+tid (i=0..3); row = i*32 + (tid>>3); phys slot = tid&7;
  // logical col slot = (tid&7) ^ ((tid>>3)&7)  [same for all i since 32%8==0]
  const int srow0 = tid >> 3;
  const int sgrp  = (tid & 7) ^ ((tid >> 3) & 7);
  size_t aoff[4], boff[4];
  #pragma unroll
  for (int i = 0; i < 4; i++){
    int row = i*32 + srow0;
    aoff[i] = (size_t)(rt*128 + row) * K + sgrp*8;
    int brow = ct*128 + row; if (brow > Nrows-1) brow = Nrows-1;
    boff[i] = (size_t)brow * K + sgrp*8;
  }

  f32x4 acc[4][4] = {};

  for (int k0 = 0; k0 < K; k0 += 64){
    #pragma unroll
    for (int i = 0; i < 4; i++){
      g2l16(A  + aoff[i] + k0, (char*)Asub + (i*256 + tid)*16);
      g2l16(Bt + boff[i] + k0, (char*)Bsub + (i*256 + tid)*16);
    }
    asm volatile("s_waitcnt vmcnt(0)" ::: "memory");
    __syncthreads();

    #pragma unroll
    for (int kk = 0; kk < 2; kk++){
      bf16x8 af[4], bfr[4];
      const int slot = (kk*4 + fq) ^ (fr & 7);
      #pragma unroll
      for (int i = 0; i < 4; i++){
        int ra = wr*64 + i*16 + fr;
        int rb = wc*64 + i*16 + fr;
        af[i]  = *(const bf16x8*)((const char*)Asub + ra*128 + slot*16);
        bfr[i] = *(const bf16x8*)((const char*)Bsub + rb*128 + slot*16);
      }
      #pragma unroll
      for (int mi = 0; mi < 4; mi++)
        #pragma unroll
        for (int ni = 0; ni < 4; ni++)
          acc[mi][ni] = __builtin_amdgcn_mfma_f32_16x16x32_bf16(af[mi], bfr[ni], acc[mi][ni], 0, 0, 0);
    }
    __syncthreads();
  }

  const int er = (lane >> 4) * 4;
  const int ec = lane & 15;
  #pragma unroll
  for (int mi = 0; mi < 4; mi++){
    #pragma unroll
    for (int ni = 0; ni < 4; ni++){
      const int row = rt*128 + wr*64 + mi*16 + er;
      const int col = ct*128 + wc*64 + ni*16 + ec;
      #pragma unroll
      for (int r = 0; r < 4; r++){
        if (OUT_BF16)
          ((unsigned short*)Cout)[(size_t)(row+r)*Npad + col] = f2bf(acc[mi][ni][r]);
        else
          ((float*)Cout)[(size_t)(row+r)*Npad + col] = acc[mi][ni][r];
      }
    }
  }
}

// ---------- per-(b,l,h) scalars -> [b][h][l] layouts ----------
__global__ __launch_bounds__(256) void k_prep_scalars(
    const unsigned short* __restrict__ proj, const float* __restrict__ dt_bias,
    float* __restrict__ DTt, float* __restrict__ logdec, float* __restrict__ lamt)
{
  int idx = blockIdx.x*256 + threadIdx.x;   // (b*1024+l)*64 + h
  int h = idx & 63, row = idx >> 6;
  int b = row >> 10, l = row & 1023;
  size_t base = (size_t)row * 8704;
  float dd_dt = bf2f(proj[base + 8448 + h]);
  float dd_A  = bf2f(proj[base + 8512 + h]);
  float trap  = bf2f(proj[base + 8576 + h]);
  float DT = softplusf(dd_dt + dt_bias[h]);
  float A  = -fmaxf(softplusf(dd_A), 1e-4f);
  size_t o = ((size_t)(b*64 + h))*1024 + l;
  DTt[o]    = DT;
  logdec[o] = A * DT;
  lamt[o]   = 1.f / (1.f + expf(-trap));
}

// ---------- rmsnorm of Braw/Craw rows (N=128) -> bf16 ----------
__global__ __launch_bounds__(128) void k_rmsnorm(
    const unsigned short* __restrict__ proj, const float* __restrict__ Bw,
    const float* __restrict__ Cw, unsigned short* __restrict__ Bb2,
    unsigned short* __restrict__ Cb2)
{
  int row = blockIdx.x, n = threadIdx.x;
  size_t base = (size_t)row * 8704;
  float bv = bf2f(proj[base + 8192 + n]);
  float cv = bf2f(proj[base + 8320 + n]);
  float sb = bv*bv, sc = cv*cv;
  #pragma unroll
  for (int m = 1; m < 64; m <<= 1){ sb += __shfl_xor(sb, m, 64); sc += __shfl_xor(sc, m, 64); }
  __shared__ float red[4];
  if ((n & 63) == 0){ red[(n>>6)*2] = sb; red[(n>>6)*2+1] = sc; }
  __syncthreads();
  sb = red[0] + red[2];
  sc = red[1] + red[3];
  float rb = rsqrtf(sb*(1.f/128.f) + 1e-5f);
  float rc = rsqrtf(sc*(1.f/128.f) + 1e-5f);
  Bb2[row*128 + n] = f2bf(bv*rb*Bw[n]);
  Cb2[row*128 + n] = f2bf(cv*rc*Cw[n]);
}

// ---------- per-chunk(128) inclusive cumsum of logdec + g = 1-lam+lam_next ----------
__global__ __launch_bounds__(256) void k_chunkscan(
    const float* __restrict__ logdec, const float* __restrict__ lamt,
    float* __restrict__ clcb, float* __restrict__ gb)
{
  int bh = blockIdx.x;
  size_t base = (size_t)bh * 1024;
  int tid = threadIdx.x;
  int e0 = tid * 4;
  float v0 = logdec[base+e0], v1 = logdec[base+e0+1], v2 = logdec[base+e0+2], v3 = logdec[base+e0+3];
  float p0 = v0, p1 = p0+v1, p2 = p1+v2, p3 = p2+v3;
  float tot = p3;
  int sub = tid & 31;
  float incl = tot;
  #pragma unroll
  for (int off = 1; off < 32; off <<= 1){
    float u = __shfl_up(incl, off, 32);
    if (sub >= off) incl += u;
  }
  float excl = incl - tot;
  clcb[base+e0]   = excl + p0;
  clcb[base+e0+1] = excl + p1;
  clcb[base+e0+2] = excl + p2;
  clcb[base+e0+3] = excl + p3;
  #pragma unroll
  for (int i = 0; i < 4; i++){
    int l = e0 + i;
    int ln = (l == 1023) ? 1023 : l + 1;
    gb[base+l] = 1.f - lamt[base+l] + lamt[base+ln];
  }
}

// ---------- phase cumsum + cos/sin tables; block per (b,h), 256 thr = 32 na x 8 chunks ----------
__global__ __launch_bounds__(256) void k_phase(
    const unsigned short* __restrict__ proj, const float* __restrict__ DTt,
    unsigned short* __restrict__ cosb, unsigned short* __restrict__ sinb)
{
  int bh = blockIdx.x, b = bh >> 6, h = bh & 63;
  int na = threadIdx.x & 31, c = threadIdx.x >> 5;
  __shared__ float part[8][32];
  const float* dtr = DTt + (size_t)bh * 1024;
  float s = 0.f;
  for (int i = 0; i < 128; i++){
    int l = c*128 + i; int row = b*1024 + l;
    float ang = bf2f(proj[(size_t)row*8704 + 8640 + na]);
    s = fmaf(ang, dtr[l], s);
  }
  part[c][na] = s;
  __syncthreads();
  float off = 0.f;
  for (int cc = 0; cc < c; cc++) off += part[cc][na];
  float ph = off;
  for (int i = 0; i < 128; i++){
    int l = c*128 + i; int row = b*1024 + l;
    float ang = bf2f(proj[(size_t)row*8704 + 8640 + na]);
    ph = fmaf(ang, dtr[l], ph);
    float sn, cs;
    __sincosf(ph, &sn, &cs);
    size_t o = ((size_t)row*64 + h)*32 + na;
    cosb[o] = f2bf(cs); sinb[o] = f2bf(sn);
  }
}

// ---------- pass A: intra-chunk y + chunk state increment G ----------
__global__ __launch_bounds__(256, 1) void k_intra(
    const unsigned short* __restrict__ proj,
    const unsigned short* __restrict__ Bb2, const unsigned short* __restrict__ Cb2,
    const float* __restrict__ Bbias, const float* __restrict__ Cbias,
    const unsigned short* __restrict__ cosb, const unsigned short* __restrict__ sinb,
    const float* __restrict__ DTt, const float* __restrict__ clcb,
    const float* __restrict__ gb, const float* __restrict__ lamt,
    const float* __restrict__ Dv, unsigned short* __restrict__ ybf,
    unsigned short* __restrict__ Gbuf)
{
  const int c = blockIdx.x & 7, bh = blockIdx.x >> 3;
  const int b = bh >> 6, h = bh & 63;
  const int tid = threadIdx.x, lane = tid & 63, wave = tid >> 6;
  const int wr = wave >> 1, wc = wave & 1;
  const int fr = lane & 15, fq = lane >> 4;

  __shared__ __align__(16) unsigned short Cs[128*128];
  __shared__ __align__(16) unsigned short Bs[128*128];   // aliased as P after barrier
  __shared__ __align__(16) unsigned short BTs[128*128];
  __shared__ __align__(16) unsigned short Uts[64*128];   // U^T: [p][j]
  __shared__ float clcs[128], lams[128], gs[128], wUs[128], dts[128];
  __shared__ float biasB[128], biasC[128];

  const int base = b*1024 + c*128;
  const size_t shbase = (size_t)bh * 1024;
  const float Dh = Dv[h];

  // phase 0: scalars
  if (tid < 128){
    int l = c*128 + tid;
    clcs[tid] = clcb[shbase + l];
    dts[tid]  = DTt[shbase + l];
    lams[tid] = lamt[shbase + l];
    gs[tid]   = gb[shbase + l];
    biasB[tid] = Bbias[h*128 + tid];
  } else {
    biasC[tid-128] = Cbias[h*128 + tid-128];
  }
  __syncthreads();
  if (tid < 128) wUs[tid] = __expf(clcs[127] - clcs[tid]) * gs[tid];

  // phase 1: stage C/B (bias+rope), B^T, U^T
  {
    const int t = tid >> 1, half = tid & 1;
    const int grow = base + t;
    const size_t roff = (size_t)grow*128 + half*64;
    if (half == 0){
      bf16x8 cc[4], sv[4];
      #pragma unroll
      for (int i = 0; i < 4; i++){
        cc[i] = *(const bf16x8*)(cosb + ((size_t)grow*64 + h)*32 + i*8);
        sv[i] = *(const bf16x8*)(sinb + ((size_t)grow*64 + h)*32 + i*8);
      }
      #pragma unroll
      for (int i = 0; i < 4; i++){
        bf16x8 vlo = *(const bf16x8*)(Cb2 + roff + i*8);
        bf16x8 vhi = *(const bf16x8*)(Cb2 + roff + 32 + i*8);
        bf16x8 olo, ohi;
        #pragma unroll
        for (int e = 0; e < 8; e++){
          float a = bf2f((unsigned short)vlo[e]) + biasC[i*8+e];
          float d = bf2f((unsigned short)vhi[e]) + biasC[32+i*8+e];
          float cf = bf2f((unsigned short)cc[i][e]);
          float sf = bf2f((unsigned short)sv[i][e]);
          olo[e] = (short)f2bf(a*cf - d*sf);
          ohi[e] = (short)f2bf(a*sf + d*cf);
        }
        ldsw_write8(Cs, t, i*8, olo);
        ldsw_write8(Cs, t, 32 + i*8, ohi);
      }
      #pragma unroll
      for (int i = 0; i < 4; i++){
        bf16x8 vlo = *(const bf16x8*)(Bb2 + roff + i*8);
        bf16x8 vhi = *(const bf16x8*)(Bb2 + roff + 32 + i*8);
        bf16x8 olo, ohi;
        #pragma unroll
        for (int e = 0; e < 8; e++){
          float a = bf2f((unsigned short)vlo[e]) + biasB[i*8+e];
          float d = bf2f((unsigned short)vhi[e]) + biasB[32+i*8+e];
          float cf = bf2f((unsigned short)cc[i][e]);
          float sf = bf2f((unsigned short)sv[i][e]);
          olo[e] = (short)f2bf(a*cf - d*sf);
          ohi[e] = (short)f2bf(a*sf + d*cf);
        }
        ldsw_write8(Bs, t, i*8, olo);
        ldsw_write8(Bs, t, 32 + i*8, ohi);
        #pragma unroll
        for (int e = 0; e < 8; e++){
          ldsw_write1(BTs, i*8+e, t, (unsigned short)olo[e]);
          ldsw_write1(BTs, 32+i*8+e, t, (unsigned short)ohi[e]);
        }
      }
    } else {
      #pragma unroll
      for (int i = 0; i < 8; i++){
        bf16x8 v = *(const bf16x8*)(Cb2 + roff + i*8);
        bf16x8 o;
        #pragma unroll
        for (int e = 0; e < 8; e++) o[e] = (short)f2bf(bf2f((unsigned short)v[e]) + biasC[64+i*8+e]);
        ldsw_write8(Cs, t, 64 + i*8, o);
      }
      #pragma unroll
      for (int i = 0; i < 8; i++){
        bf16x8 v = *(const bf16x8*)(Bb2 + roff + i*8);
        bf16x8 o;
        #pragma unroll
        for (int e = 0; e < 8; e++) o[e] = (short)f2bf(bf2f((unsigned short)v[e]) + biasB[64+i*8+e]);
        ldsw_write8(Bs, t, 64 + i*8, o);
        #pragma unroll
        for (int e = 0; e < 8; e++) ldsw_write1(BTs, 64+i*8+e, t, (unsigned short)o[e]);
      }
    }
  }
  {
    const int p = tid & 63, jg = tid >> 6;
    #pragma unroll 4
    for (int i = 0; i < 32; i++){
      int j = jg*32 + i;
      size_t pb = (size_t)(base + j) * 8704;
      float x  = bf2f(proj[pb + 4096 + h*64 + p]);
      ldsw_write1(Uts, p, j, f2bf(x * dts[j]));
    }
  }
  __syncthreads();

  // MFMA1: scores[t][j] = C . B^T
  f32x4 acc1[4][4];
  #pragma unroll
  for (int mi = 0; mi < 4; mi++)
    #pragma unroll
    for (int ni = 0; ni < 4; ni++)
      acc1[mi][ni] = (f32x4){0.f,0.f,0.f,0.f};
  #pragma unroll
  for (int ks = 0; ks < 4; ks++){
    bf16x8 af[4], bj[4];
    #pragma unroll
    for (int mi = 0; mi < 4; mi++) af[mi] = ldsw_read8(Cs, wr*64+mi*16+fr, ks*32+fq*8);
    #pragma unroll
    for (int ni = 0; ni < 4; ni++) bj[ni] = ldsw_read8(Bs, wc*64+ni*16+fr, ks*32+fq*8);
    #pragma unroll
    for (int mi = 0; mi < 4; mi++)
      #pragma unroll
      for (int ni = 0; ni < 4; ni++)
        acc1[mi][ni] = __builtin_amdgcn_mfma_f32_16x16x32_bf16(af[mi], bj[ni], acc1[mi][ni], 0,0,0);
  }
  // weight epilogue: P = W o scores
  unsigned short pr[4][4][4];
  int jj[4]; float clcj[4], gj[4];
  #pragma unroll
  for (int ni = 0; ni < 4; ni++){ jj[ni] = wc*64+ni*16+fr; clcj[ni] = clcs[jj[ni]]; gj[ni] = gs[jj[ni]]; }
  #pragma unroll
  for (int mi = 0; mi < 4; mi++){
    #pragma unroll
    for (int r = 0; r < 4; r++){
      int t = wr*64+mi*16+fq*4+r;
      float ct = clcs[t], lt = lams[t];
      #pragma unroll
      for (int ni = 0; ni < 4; ni++){
        int j = jj[ni];
        float w = (j < t) ? __expf(ct - clcj[ni])*gj[ni] : ((j == t) ? (1.f - lt) : 0.f);
        pr[mi][ni][r] = f2bf(acc1[mi][ni][r] * w);
      }
    }
  }
  __syncthreads();                     // all MFMA1 reads of Bs complete
  #pragma unroll
  for (int mi = 0; mi < 4; mi++)
    #pragma unroll
    for (int ni = 0; ni < 4; ni++)
      #pragma unroll
      for (int r = 0; r < 4; r++)
        ldsw_write1(Bs, wr*64+mi*16+fq*4+r, wc*64+ni*16+fr, pr[mi][ni][r]);
  __syncthreads();

  // MFMA2: y_intra[t][p] = P . U
  f32x4 acc2[4][2];
  #pragma unroll
  for (int mi = 0; mi < 4; mi++)
    #pragma unroll
    for (int ni = 0; ni < 2; ni++)
      acc2[mi][ni] = (f32x4){0.f,0.f,0.f,0.f};
  #pragma unroll
  for (int ks = 0; ks < 4; ks++){
    bf16x8 af[4], uj[2];
    #pragma unroll
    for (int mi = 0; mi < 4; mi++) af[mi] = ldsw_read8(Bs, wr*64+mi*16+fr, ks*32+fq*8);
    #pragma unroll
    for (int ni = 0; ni < 2; ni++) uj[ni] = ldsw_read8(Uts, wc*32+ni*16+fr, ks*32+fq*8);
    #pragma unroll
    for (int mi = 0; mi < 4; mi++)
      #pragma unroll
      for (int ni = 0; ni < 2; ni++)
        acc2[mi][ni] = __builtin_amdgcn_mfma_f32_16x16x32_bf16(af[mi], uj[ni], acc2[mi][ni], 0,0,0);
  }
  // MFMA4: G[p][n] = (wU o U) . B
  f32x4 accS[2][4];
  #pragma unroll
  for (int mi = 0; mi < 2; mi++)
    #pragma unroll
    for (int ni = 0; ni < 4; ni++)
      accS[mi][ni] = (f32x4){0.f,0.f,0.f,0.f};
  #pragma unroll
  for (int ks = 0; ks < 4; ks++){
    bf16x8 au[2], bn[4];
    #pragma unroll
    for (int mi = 0; mi < 2; mi++){
      bf16x8 raw = ldsw_read8(Uts, wr*32+mi*16+fr, ks*32+fq*8);
      #pragma unroll
      for (int e = 0; e < 8; e++){
        float f = bf2f((unsigned short)raw[e]) * wUs[ks*32+fq*8+e];
        au[mi][e] = (short)f2bf(f);
      }
    }
    #pragma unroll
    for (int ni = 0; ni < 4; ni++) bn[ni] = ldsw_read8(BTs, wc*64+ni*16+fr, ks*32+fq*8);
    #pragma unroll
    for (int mi = 0; mi < 2; mi++)
      #pragma unroll
      for (int ni = 0; ni < 4; ni++)
        accS[mi][ni] = __builtin_amdgcn_mfma_f32_16x16x32_bf16(au[mi], bn[ni], accS[mi][ni], 0,0,0);
  }

  // stores: y_intra + D*x (ungated) and G
  #pragma unroll
  for (int mi = 0; mi < 4; mi++){
    #pragma unroll
    for (int ni = 0; ni < 2; ni++){
      #pragma unroll
      for (int r = 0; r < 4; r++){
        int t = wr*64+mi*16+fq*4+r;
        int p = wc*32+ni*16+fr;
        float xv = bf2f(ldsw_read1(Uts, p, t)) / fmaxf(dts[t], 1e-30f);
        float o = acc2[mi][ni][r] + Dh*xv;
        ybf[(size_t)(base + t)*4096 + h*64 + p] = f2bf(o);
      }
    }
  }
  #pragma unroll
  for (int mi = 0; mi < 2; mi++)
    #pragma unroll
    for (int ni = 0; ni < 4; ni++)
      #pragma unroll
      for (int r = 0; r < 4; r++){
        int p = wr*32+mi*16+fq*4+r;
        int n = wc*64+ni*16+fr;
        Gbuf[(size_t)blockIdx.x*8192 + p*128 + n] = f2bf(accS[mi][ni][r]);
      }
}

// ---------- pass B: scan over 8 chunks; Gbuf[c] <- S_prev(c), S = decEnd*S + G ----------
__global__ __launch_bounds__(256) void k_scanstate(
    const float* __restrict__ clcb, unsigned short* __restrict__ Gbuf)
{
  const int bh = blockIdx.x, tid = threadIdx.x;
  float S[32];
  #pragma unroll
  for (int i = 0; i < 32; i++) S[i] = 0.f;
  const size_t gbase = (size_t)bh*65536 + (size_t)tid*32;
  for (int c = 0; c < 8; c++){
    float decEnd = __expf(clcb[(size_t)bh*1024 + c*128 + 127]);
    unsigned short* p = Gbuf + gbase + (size_t)c*8192;
    bf16x8 g[4], s[4];
    #pragma unroll
    for (int i = 0; i < 4; i++) g[i] = *(const bf16x8*)(p + i*8);
    #pragma unroll
    for (int i = 0; i < 4; i++)
      #pragma unroll
      for (int e = 0; e < 8; e++) s[i][e] = (short)f2bf(S[i*8+e]);
    #pragma unroll
    for (int i = 0; i < 4; i++) *(bf16x8*)(p + i*8) = s[i];
    #pragma unroll
    for (int i = 0; i < 4; i++)
      #pragma unroll
      for (int e = 0; e < 8; e++)
        S[i*8+e] = decEnd*S[i*8+e] + bf2f((unsigned short)g[i][e]);
  }
}

// ---------- pass C: y = (y_intra + exp(clc_t) * C_t . S_prev^T) * silu(z) ----------
__global__ __launch_bounds__(256) void k_inter(
    const unsigned short* __restrict__ proj,
    const unsigned short* __restrict__ Cb2, const float* __restrict__ Cbias,
    const unsigned short* __restrict__ cosb, const unsigned short* __restrict__ sinb,
    const float* __restrict__ clcb, const unsigned short* __restrict__ Sprev,
    unsigned short* __restrict__ ybf)
{
  const int c = blockIdx.x & 7, bh = blockIdx.x >> 3;
  const int b = bh >> 6, h = bh & 63;
  const int tid = threadIdx.x, lane = tid & 63, wave = tid >> 6;
  const int wr = wave >> 1, wc = wave & 1;
  const int fr = lane & 15, fq = lane >> 4;

  __shared__ __align__(16) unsigned short Cs[128*128];
  __shared__ __align__(16) unsigned short Ss[64*128];
  __shared__ float expclcs[128], biasC[128];

  const int base = b*1024 + c*128;

  if (tid < 128){
    expclcs[tid] = __expf(clcb[(size_t)bh*1024 + c*128 + tid]);
    biasC[tid] = Cbias[h*128 + tid];
  }
  __syncthreads();

  // stage C (bias+rope)
  {
    const int t = tid >> 1, half = tid & 1;
    const int grow = base + t;
    const size_t roff = (size_t)grow*128 + half*64;
    if (half == 0){
      bf16x8 cc[4], sv[4];
      #pragma unroll
      for (int i = 0; i < 4; i++){
        cc[i] = *(const bf16x8*)(cosb + ((size_t)grow*64 + h)*32 + i*8);
        sv[i] = *(const bf16x8*)(sinb + ((size_t)grow*64 + h)*32 + i*8);
      }
      #pragma unroll
      for (int i = 0; i < 4; i++){
        bf16x8 vlo = *(const bf16x8*)(Cb2 + roff + i*8);
        bf16x8 vhi = *(const bf16x8*)(Cb2 + roff + 32 + i*8);
        bf16x8 olo, ohi;
        #pragma unroll
        for (int e = 0; e < 8; e++){
          float a = bf2f((unsigned short)vlo[e]) + biasC[i*8+e];
          float d = bf2f((unsigned short)vhi[e]) + biasC[32+i*8+e];
          float cf = bf2f((unsigned short)cc[i][e]);
          float sf = bf2f((unsigned short)sv[i][e]);
          olo[e] = (short)f2bf(a*cf - d*sf);
          ohi[e] = (short)f2bf(a*sf + d*cf);
        }
        ldsw_write8(Cs, t, i*8, olo);
        ldsw_write8(Cs, t, 32 + i*8, ohi);
      }
    } else {
      #pragma unroll
      for (int i = 0; i < 8; i++){
        bf16x8 v = *(const bf16x8*)(Cb2 + roff + i*8);
        bf16x8 o;
        #pragma unroll
        for (int e = 0; e < 8; e++) o[e] = (short)f2bf(bf2f((unsigned short)v[e]) + biasC[64+i*8+e]);
        ldsw_write8(Cs, t, 64 + i*8, o);
      }
    }
  }
  // stage S_prev (reg -> swizzled LDS)
  {
    const unsigned short* src = Sprev + (size_t)blockIdx.x*8192 + (size_t)tid*32;
    #pragma unroll
    for (int i = 0; i < 4; i++){
      bf16x8 v = *(const bf16x8*)(src + i*8);
      int f = tid*32 + i*8;
      ldsw_write8(Ss, f >> 7, f & 127, v);
    }
  }
  __syncthreads();

  // MFMA: Yinter[t][p] = C . S_prev^T
  f32x4 acc[4][2];
  #pragma unroll
  for (int mi = 0; mi < 4; mi++)
    #pragma unroll
    for (int ni = 0; ni < 2; ni++)
      acc[mi][ni] = (f32x4){0.f,0.f,0.f,0.f};
  #pragma unroll
  for (int ks = 0; ks < 4; ks++){
    bf16x8 af[4], sj[2];
    #pragma unroll
    for (int mi = 0; mi < 4; mi++) af[mi] = ldsw_read8(Cs, wr*64+mi*16+fr, ks*32+fq*8);
    #pragma unroll
    for (int ni = 0; ni < 2; ni++) sj[ni] = ldsw_read8(Ss, wc*32+ni*16+fr, ks*32+fq*8);
    #pragma unroll
    for (int mi = 0; mi < 4; mi++)
      #pragma unroll
      for (int ni = 0; ni < 2; ni++)
        acc[mi][ni] = __builtin_amdgcn_mfma_f32_16x16x32_bf16(af[mi], sj[ni], acc[mi][ni], 0,0,0);
  }

  // epilogue: y = (y_intra + expclc*Yinter) * silu(z)
  #pragma unroll
  for (int mi = 0; mi < 4; mi++){
    #pragma unroll
    for (int ni = 0; ni < 2; ni++){
      #pragma unroll
      for (int r = 0; r < 4; r++){
        int t = wr*64+mi*16+fq*4+r;
        int p = wc*32+ni*16+fr;
        size_t yoff = (size_t)(base + t)*4096 + h*64 + p;
        float y = bf2f(ybf[yoff]) + expclcs[t]*acc[mi][ni][r];
        float zv = bf2f(proj[(size_t)(base + t)*8704 + h*64 + p]);
        float sl = zv / (1.f + __expf(-zv));
        ybf[yoff] = f2bf(y * sl);
      }
    }
  }
}

// ---------- launch ----------
extern "C" void kernel_launch(void* const* d_in, const int* in_sizes, int n_in,
                              void* d_out, int out_size, void* d_ws, size_t ws_size,
                              hipStream_t stream)
{
  const float* hs    = (const float*)d_in[0];
  const float* w1    = (const float*)d_in[1];
  const float* dtb   = (const float*)d_in[2];
  const float* Bbias = (const float*)d_in[3];
  const float* Cbias = (const float*)d_in[4];
  const float* Bw    = (const float*)d_in[5];
  const float* Cw    = (const float*)d_in[6];
  const float* Dv    = (const float*)d_in[7];
  const float* wo    = (const float*)d_in[8];
  float* out = (float*)d_out;
  char* ws = (char*)d_ws;

  unsigned short* projbf = (unsigned short*)(ws + 0UL);
  unsigned short* W1bf   = (unsigned short*)(ws + 35651584UL);
  unsigned short* Gbuf   = W1bf;                                  // post-GEMM1
  unsigned short* Wobf   = W1bf;                                  // post-k_inter
  unsigned short* ybf    = (unsigned short*)(ws + 52428800UL);
  unsigned short* hsbf   = (unsigned short*)(ws + 71172096UL);
  unsigned short* cosb   = hsbf;                                  // post-GEMM1
  unsigned short* sinb   = (unsigned short*)(ws + 79560704UL);
  float* DTt    = (float*)(ws + 87949312UL);
  float* logdec = (float*)(ws + 88473600UL);
  float* lamt   = (float*)(ws + 88997888UL);
  float* clcb   = (float*)(ws + 89522176UL);
  float* gb     = (float*)(ws + 90046464UL);
  unsigned short* Bb2 = (unsigned short*)(ws + 90570752UL);
  unsigned short* Cb2 = (unsigned short*)(ws + 91095040UL);
  if (ws_size < 91619328UL) return;

  (void)in_sizes; (void)n_in; (void)out_size;

  k_f32_to_bf16<<<17344, 256, 0, stream>>>(w1, W1bf, 17760256L);
  k_f32_to_bf16<<<4096,  256, 0, stream>>>(hs, hsbf, 4194304L);
  k_gemm_bt<true><<<16*68, 256, 0, stream>>>(hsbf, W1bf, projbf, 2048, 8672, 8704, 68);
  k_prep_scalars<<<512, 256, 0, stream>>>(projbf, dtb, DTt, logdec, lamt);
  k_rmsnorm<<<2048, 128, 0, stream>>>(projbf, Bw, Cw, Bb2, Cb2);
  k_chunkscan<<<128, 256, 0, stream>>>(logdec, lamt, clcb, gb);
  k_phase<<<128, 256, 0, stream>>>(projbf, DTt, cosb, sinb);
  k_intra<<<1024, 256, 0, stream>>>(projbf, Bb2, Cb2, Bbias, Cbias,
                                    cosb, sinb, DTt, clcb, gb, lamt, Dv, ybf, Gbuf);
  k_scanstate<<<128, 256, 0, stream>>>(clcb, Gbuf);
  k_inter<<<1024, 256, 0, stream>>>(projbf, Cb2, Cbias, cosb, sinb, clcb, Gbuf, ybf);
  k_f32_to_bf16<<<8192, 256, 0, stream>>>(wo, Wobf, 8388608L);
  k_gemm_bt<false><<<16*16, 256, 0, stream>>>(ybf, Wobf, out, 4096, 2048, 2048, 16);
}

// Round 6
// 331.329 us; speedup vs baseline: 6.2990x; 1.0301x over previous
//
#include <hip/hip_runtime.h>
#include <hip/hip_bf16.h>
#include <cstdint>
#include <cstddef>

#define DEVINL __device__ __forceinline__

typedef __attribute__((ext_vector_type(8))) short bf16x8;
typedef __attribute__((ext_vector_type(4))) float f32x4;

// ---------- helpers ----------
DEVINL float bf2f(unsigned short u){
  union { unsigned u32; float f; } cv; cv.u32 = ((unsigned)u) << 16; return cv.f;
}
DEVINL unsigned short f2bf(float f){
  union { float f; unsigned u32; } cv; cv.f = f;
  unsigned u = cv.u32;
  return (unsigned short)((u + 0x7FFFu + ((u >> 16) & 1u)) >> 16);  // RNE
}
DEVINL float softplusf(float x){ return x > 20.f ? x : log1pf(expf(x)); }

DEVINL void g2l16(const void* gptr, void* ldsptr){
  __builtin_amdgcn_global_load_lds(
      (const __attribute__((address_space(1))) unsigned int*)gptr,
      (__attribute__((address_space(3))) unsigned int*)(uintptr_t)ldsptr,
      16, 0, 0);
}

// swizzled LDS access for 256-byte-row tiles (128 bf16 cols)
DEVINL int swzb(int row, int col){ return row*256 + ((col*2) ^ ((row&7)<<4)); }
DEVINL void ldsw_write8(unsigned short* b, int row, int col, bf16x8 v){
  *(bf16x8*)((char*)b + swzb(row,col)) = v;
}
DEVINL bf16x8 ldsw_read8(const unsigned short* b, int row, int col){
  return *(const bf16x8*)((const char*)b + swzb(row,col));
}
DEVINL void ldsw_write1(unsigned short* b, int row, int col, unsigned short v){
  *(unsigned short*)((char*)b + swzb(row,col)) = v;
}
DEVINL unsigned short ldsw_read1(const unsigned short* b, int row, int col){
  return *(const unsigned short*)((const char*)b + swzb(row,col));
}

// ---------- f32 -> bf16 conversion ----------
__global__ __launch_bounds__(256) void k_f32_to_bf16(
    const float* __restrict__ in, unsigned short* __restrict__ out, long n)
{
  long i = ((long)blockIdx.x * 256 + threadIdx.x) * 4;
  if (i + 3 < n){
    float4 v = *(const float4*)(in + i);
    unsigned long long pk =
        (unsigned long long)f2bf(v.x)
      | ((unsigned long long)f2bf(v.y) << 16)
      | ((unsigned long long)f2bf(v.z) << 32)
      | ((unsigned long long)f2bf(v.w) << 48);
    *(unsigned long long*)(out + i) = pk;
  }
}

// ---------- bf16 GEMM, both operands K-major, C = A * Bt^T ----------
// 128x128 tile, BK=64, swizzled LDS (slot ^= row&7), 2D XCD-local tile partition:
// XCD x owns a (tmx x tnx) tile sub-grid, rt-inner order (A-panels L2-resident).
template<bool OUT_BF16>
__global__ __launch_bounds__(256) void k_gemm_bt(
    const unsigned short* __restrict__ A,
    const unsigned short* __restrict__ Bt,
    void* __restrict__ Cout,
    int K, int Nrows, int Npad, int xm, int tmx, int tnx)
{
  __shared__ unsigned short Asub[128*64];
  __shared__ unsigned short Bsub[128*64];
  const int tid = threadIdx.x;
  // bijective 2D XCD partition: requires gridDim.x == 8*tmx*tnx
  const int x = blockIdx.x & 7, i = blockIdx.x >> 3;
  const int rt = (x % xm) * tmx + (i % tmx);
  const int ct = (x / xm) * tnx + (i / tmx);
  const int lane = tid & 63, wave = tid >> 6;
  const int wr = wave >> 1, wc = wave & 1;
  const int fr = lane & 15;
  const int fq = lane >> 4;

  // staging map: pos = j*256+tid (j=0..3); row = j*32 + (tid>>3); phys slot = tid&7;
  // logical col slot = (tid&7) ^ ((tid>>3)&7)
  const int srow0 = tid >> 3;
  const int sgrp  = (tid & 7) ^ ((tid >> 3) & 7);
  size_t aoff[4], boff[4];
  #pragma unroll
  for (int j = 0; j < 4; j++){
    int row = j*32 + srow0;
    aoff[j] = (size_t)(rt*128 + row) * K + sgrp*8;
    int brow = ct*128 + row; if (brow > Nrows-1) brow = Nrows-1;
    boff[j] = (size_t)brow * K + sgrp*8;
  }

  f32x4 acc[4][4] = {};

  for (int k0 = 0; k0 < K; k0 += 64){
    #pragma unroll
    for (int j = 0; j < 4; j++){
      g2l16(A  + aoff[j] + k0, (char*)Asub + (j*256 + tid)*16);
      g2l16(Bt + boff[j] + k0, (char*)Bsub + (j*256 + tid)*16);
    }
    asm volatile("s_waitcnt vmcnt(0)" ::: "memory");
    __syncthreads();

    #pragma unroll
    for (int kk = 0; kk < 2; kk++){
      bf16x8 af[4], bfr[4];
      const int slot = (kk*4 + fq) ^ (fr & 7);
      #pragma unroll
      for (int j = 0; j < 4; j++){
        int ra = wr*64 + j*16 + fr;
        int rb = wc*64 + j*16 + fr;
        af[j]  = *(const bf16x8*)((const char*)Asub + ra*128 + slot*16);
        bfr[j] = *(const bf16x8*)((const char*)Bsub + rb*128 + slot*16);
      }
      #pragma unroll
      for (int mi = 0; mi < 4; mi++)
        #pragma unroll
        for (int ni = 0; ni < 4; ni++)
          acc[mi][ni] = __builtin_amdgcn_mfma_f32_16x16x32_bf16(af[mi], bfr[ni], acc[mi][ni], 0, 0, 0);
    }
    __syncthreads();
  }

  const int er = (lane >> 4) * 4;
  const int ec = lane & 15;
  #pragma unroll
  for (int mi = 0; mi < 4; mi++){
    #pragma unroll
    for (int ni = 0; ni < 4; ni++){
      const int row = rt*128 + wr*64 + mi*16 + er;
      const int col = ct*128 + wc*64 + ni*16 + ec;
      #pragma unroll
      for (int r = 0; r < 4; r++){
        if (OUT_BF16)
          ((unsigned short*)Cout)[(size_t)(row+r)*Npad + col] = f2bf(acc[mi][ni][r]);
        else
          ((float*)Cout)[(size_t)(row+r)*Npad + col] = acc[mi][ni][r];
      }
    }
  }
}

// ---------- fused: rmsnorm of Braw/Craw (N=128) -> bf16  +  per-(b,l,h) scalars ----------
__global__ __launch_bounds__(128) void k_rmsprep(
    const unsigned short* __restrict__ proj, const float* __restrict__ Bw,
    const float* __restrict__ Cw, const float* __restrict__ dt_bias,
    unsigned short* __restrict__ Bb2, unsigned short* __restrict__ Cb2,
    float* __restrict__ DTt, float* __restrict__ logdec, float* __restrict__ lamt)
{
  int row = blockIdx.x, n = threadIdx.x;
  size_t base = (size_t)row * 8704;
  float bv = bf2f(proj[base + 8192 + n]);
  float cv = bf2f(proj[base + 8320 + n]);
  float sb = bv*bv, sc = cv*cv;
  #pragma unroll
  for (int m = 1; m < 64; m <<= 1){ sb += __shfl_xor(sb, m, 64); sc += __shfl_xor(sc, m, 64); }
  __shared__ float red[4];
  if ((n & 63) == 0){ red[(n>>6)*2] = sb; red[(n>>6)*2+1] = sc; }
  __syncthreads();
  sb = red[0] + red[2];
  sc = red[1] + red[3];
  float rb = rsqrtf(sb*(1.f/128.f) + 1e-5f);
  float rc = rsqrtf(sc*(1.f/128.f) + 1e-5f);
  Bb2[row*128 + n] = f2bf(bv*rb*Bw[n]);
  Cb2[row*128 + n] = f2bf(cv*rc*Cw[n]);
  // fused per-(row,h) scalars (threads 0..63)
  if (n < 64){
    int h = n, b = row >> 10, l = row & 1023;
    float dd_dt = bf2f(proj[base + 8448 + h]);
    float dd_A  = bf2f(proj[base + 8512 + h]);
    float trap  = bf2f(proj[base + 8576 + h]);
    float DT = softplusf(dd_dt + dt_bias[h]);
    float A  = -fmaxf(softplusf(dd_A), 1e-4f);
    size_t o = ((size_t)(b*64 + h))*1024 + l;
    DTt[o]    = DT;
    logdec[o] = A * DT;
    lamt[o]   = 1.f / (1.f + expf(-trap));
  }
}

// ---------- fused: per-chunk cumsum of logdec + g  THEN  phase cumsum + cos/sin ----------
// block per (b,h), 256 threads
__global__ __launch_bounds__(256) void k_phase(
    const unsigned short* __restrict__ proj, const float* __restrict__ DTt,
    const float* __restrict__ logdec, const float* __restrict__ lamt,
    float* __restrict__ clcb, float* __restrict__ gb,
    unsigned short* __restrict__ cosb, unsigned short* __restrict__ sinb)
{
  int bh = blockIdx.x, b = bh >> 6, h = bh & 63;
  int tid = threadIdx.x;
  size_t sbase = (size_t)bh * 1024;
  // --- chunkscan part: per-128 inclusive cumsum of logdec; g = 1-lam+lam_next ---
  {
    int e0 = tid * 4;
    float v0 = logdec[sbase+e0], v1 = logdec[sbase+e0+1],
          v2 = logdec[sbase+e0+2], v3 = logdec[sbase+e0+3];
    float p0 = v0, p1 = p0+v1, p2 = p1+v2, p3 = p2+v3;
    float tot = p3;
    int sub = tid & 31;
    float incl = tot;
    #pragma unroll
    for (int off = 1; off < 32; off <<= 1){
      float u = __shfl_up(incl, off, 32);
      if (sub >= off) incl += u;
    }
    float excl = incl - tot;
    clcb[sbase+e0]   = excl + p0;
    clcb[sbase+e0+1] = excl + p1;
    clcb[sbase+e0+2] = excl + p2;
    clcb[sbase+e0+3] = excl + p3;
    #pragma unroll
    for (int q = 0; q < 4; q++){
      int l = e0 + q;
      int ln = (l == 1023) ? 1023 : l + 1;
      gb[sbase+l] = 1.f - lamt[sbase+l] + lamt[sbase+ln];
    }
  }
  // --- phase part: 32 na x 8 chunks ---
  int na = tid & 31, c = tid >> 5;
  __shared__ float part[8][32];
  const float* dtr = DTt + sbase;
  float s = 0.f;
  for (int q = 0; q < 128; q++){
    int l = c*128 + q; int row = b*1024 + l;
    float ang = bf2f(proj[(size_t)row*8704 + 8640 + na]);
    s = fmaf(ang, dtr[l], s);
  }
  part[c][na] = s;
  __syncthreads();
  float off = 0.f;
  for (int cc = 0; cc < c; cc++) off += part[cc][na];
  float ph = off;
  for (int q = 0; q < 128; q++){
    int l = c*128 + q; int row = b*1024 + l;
    float ang = bf2f(proj[(size_t)row*8704 + 8640 + na]);
    ph = fmaf(ang, dtr[l], ph);
    float sn, cs;
    __sincosf(ph, &sn, &cs);
    size_t o = ((size_t)row*64 + h)*32 + na;
    cosb[o] = f2bf(cs); sinb[o] = f2bf(sn);
  }
}

// ---------- pass A: intra-chunk y + chunk state increment G ----------
__global__ __launch_bounds__(256, 1) void k_intra(
    const unsigned short* __restrict__ proj,
    const unsigned short* __restrict__ Bb2, const unsigned short* __restrict__ Cb2,
    const float* __restrict__ Bbias, const float* __restrict__ Cbias,
    const unsigned short* __restrict__ cosb, const unsigned short* __restrict__ sinb,
    const float* __restrict__ DTt, const float* __restrict__ clcb,
    const float* __restrict__ gb, const float* __restrict__ lamt,
    const float* __restrict__ Dv, unsigned short* __restrict__ ybf,
    unsigned short* __restrict__ Gbuf)
{
  const int c = blockIdx.x & 7, bh = blockIdx.x >> 3;
  const int b = bh >> 6, h = bh & 63;
  const int tid = threadIdx.x, lane = tid & 63, wave = tid >> 6;
  const int wr = wave >> 1, wc = wave & 1;
  const int fr = lane & 15, fq = lane >> 4;

  __shared__ __align__(16) unsigned short Cs[128*128];
  __shared__ __align__(16) unsigned short Bs[128*128];   // aliased as P after barrier
  __shared__ __align__(16) unsigned short BTs[128*128];
  __shared__ __align__(16) unsigned short Uts[64*128];   // U^T: [p][j]
  __shared__ float clcs[128], lams[128], gs[128], wUs[128], dts[128];
  __shared__ float biasB[128], biasC[128];

  const int base = b*1024 + c*128;
  const size_t shbase = (size_t)bh * 1024;
  const float Dh = Dv[h];

  // phase 0: scalars
  if (tid < 128){
    int l = c*128 + tid;
    clcs[tid] = clcb[shbase + l];
    dts[tid]  = DTt[shbase + l];
    lams[tid] = lamt[shbase + l];
    gs[tid]   = gb[shbase + l];
    biasB[tid] = Bbias[h*128 + tid];
  } else {
    biasC[tid-128] = Cbias[h*128 + tid-128];
  }
  __syncthreads();
  if (tid < 128) wUs[tid] = __expf(clcs[127] - clcs[tid]) * gs[tid];

  // phase 1: stage C/B (bias+rope), B^T, U^T
  {
    const int t = tid >> 1, half = tid & 1;
    const int grow = base + t;
    const size_t roff = (size_t)grow*128 + half*64;
    if (half == 0){
      bf16x8 cc[4], sv[4];
      #pragma unroll
      for (int j = 0; j < 4; j++){
        cc[j] = *(const bf16x8*)(cosb + ((size_t)grow*64 + h)*32 + j*8);
        sv[j] = *(const bf16x8*)(sinb + ((size_t)grow*64 + h)*32 + j*8);
      }
      #pragma unroll
      for (int j = 0; j < 4; j++){
        bf16x8 vlo = *(const bf16x8*)(Cb2 + roff + j*8);
        bf16x8 vhi = *(const bf16x8*)(Cb2 + roff + 32 + j*8);
        bf16x8 olo, ohi;
        #pragma unroll
        for (int e = 0; e < 8; e++){
          float a = bf2f((unsigned short)vlo[e]) + biasC[j*8+e];
          float d = bf2f((unsigned short)vhi[e]) + biasC[32+j*8+e];
          float cf = bf2f((unsigned short)cc[j][e]);
          float sf = bf2f((unsigned short)sv[j][e]);
          olo[e] = (short)f2bf(a*cf - d*sf);
          ohi[e] = (short)f2bf(a*sf + d*cf);
        }
        ldsw_write8(Cs, t, j*8, olo);
        ldsw_write8(Cs, t, 32 + j*8, ohi);
      }
      #pragma unroll
      for (int j = 0; j < 4; j++){
        bf16x8 vlo = *(const bf16x8*)(Bb2 + roff + j*8);
        bf16x8 vhi = *(const bf16x8*)(Bb2 + roff + 32 + j*8);
        bf16x8 olo, ohi;
        #pragma unroll
        for (int e = 0; e < 8; e++){
          float a = bf2f((unsigned short)vlo[e]) + biasB[j*8+e];
          float d = bf2f((unsigned short)vhi[e]) + biasB[32+j*8+e];
          float cf = bf2f((unsigned short)cc[j][e]);
          float sf = bf2f((unsigned short)sv[j][e]);
          olo[e] = (short)f2bf(a*cf - d*sf);
          ohi[e] = (short)f2bf(a*sf + d*cf);
        }
        ldsw_write8(Bs, t, j*8, olo);
        ldsw_write8(Bs, t, 32 + j*8, ohi);
        #pragma unroll
        for (int e = 0; e < 8; e++){
          ldsw_write1(BTs, j*8+e, t, (unsigned short)olo[e]);
          ldsw_write1(BTs, 32+j*8+e, t, (unsigned short)ohi[e]);
        }
      }
    } else {
      #pragma unroll
      for (int j = 0; j < 8; j++){
        bf16x8 v = *(const bf16x8*)(Cb2 + roff + j*8);
        bf16x8 o;
        #pragma unroll
        for (int e = 0; e < 8; e++) o[e] = (short)f2bf(bf2f((unsigned short)v[e]) + biasC[64+j*8+e]);
        ldsw_write8(Cs, t, 64 + j*8, o);
      }
      #pragma unroll
      for (int j = 0; j < 8; j++){
        bf16x8 v = *(const bf16x8*)(Bb2 + roff + j*8);
        bf16x8 o;
        #pragma unroll
        for (int e = 0; e < 8; e++) o[e] = (short)f2bf(bf2f((unsigned short)v[e]) + biasB[64+j*8+e]);
        ldsw_write8(Bs, t, 64 + j*8, o);
        #pragma unroll
        for (int e = 0; e < 8; e++) ldsw_write1(BTs, 64+j*8+e, t, (unsigned short)o[e]);
      }
    }
  }
  {
    const int p = tid & 63, jg = tid >> 6;
    #pragma unroll 4
    for (int q = 0; q < 32; q++){
      int j = jg*32 + q;
      size_t pb = (size_t)(base + j) * 8704;
      float xx = bf2f(proj[pb + 4096 + h*64 + p]);
      ldsw_write1(Uts, p, j, f2bf(xx * dts[j]));
    }
  }
  __syncthreads();

  // MFMA1: scores[t][j] = C . B^T
  f32x4 acc1[4][4];
  #pragma unroll
  for (int mi = 0; mi < 4; mi++)
    #pragma unroll
    for (int ni = 0; ni < 4; ni++)
      acc1[mi][ni] = (f32x4){0.f,0.f,0.f,0.f};
  #pragma unroll
  for (int ks = 0; ks < 4; ks++){
    bf16x8 af[4], bj[4];
    #pragma unroll
    for (int mi = 0; mi < 4; mi++) af[mi] = ldsw_read8(Cs, wr*64+mi*16+fr, ks*32+fq*8);
    #pragma unroll
    for (int ni = 0; ni < 4; ni++) bj[ni] = ldsw_read8(Bs, wc*64+ni*16+fr, ks*32+fq*8);
    #pragma unroll
    for (int mi = 0; mi < 4; mi++)
      #pragma unroll
      for (int ni = 0; ni < 4; ni++)
        acc1[mi][ni] = __builtin_amdgcn_mfma_f32_16x16x32_bf16(af[mi], bj[ni], acc1[mi][ni], 0,0,0);
  }
  // weight epilogue: P = W o scores
  unsigned short pr[4][4][4];
  int jj[4]; float clcj[4], gj[4];
  #pragma unroll
  for (int ni = 0; ni < 4; ni++){ jj[ni] = wc*64+ni*16+fr; clcj[ni] = clcs[jj[ni]]; gj[ni] = gs[jj[ni]]; }
  #pragma unroll
  for (int mi = 0; mi < 4; mi++){
    #pragma unroll
    for (int r = 0; r < 4; r++){
      int t = wr*64+mi*16+fq*4+r;
      float ct_ = clcs[t], lt = lams[t];
      #pragma unroll
      for (int ni = 0; ni < 4; ni++){
        int j = jj[ni];
        float w = (j < t) ? __expf(ct_ - clcj[ni])*gj[ni] : ((j == t) ? (1.f - lt) : 0.f);
        pr[mi][ni][r] = f2bf(acc1[mi][ni][r] * w);
      }
    }
  }
  __syncthreads();                     // all MFMA1 reads of Bs complete
  #pragma unroll
  for (int mi = 0; mi < 4; mi++)
    #pragma unroll
    for (int ni = 0; ni < 4; ni++)
      #pragma unroll
      for (int r = 0; r < 4; r++)
        ldsw_write1(Bs, wr*64+mi*16+fq*4+r, wc*64+ni*16+fr, pr[mi][ni][r]);
  __syncthreads();

  // MFMA2: y_intra[t][p] = P . U
  f32x4 acc2[4][2];
  #pragma unroll
  for (int mi = 0; mi < 4; mi++)
    #pragma unroll
    for (int ni = 0; ni < 2; ni++)
      acc2[mi][ni] = (f32x4){0.f,0.f,0.f,0.f};
  #pragma unroll
  for (int ks = 0; ks < 4; ks++){
    bf16x8 af[4], uj[2];
    #pragma unroll
    for (int mi = 0; mi < 4; mi++) af[mi] = ldsw_read8(Bs, wr*64+mi*16+fr, ks*32+fq*8);
    #pragma unroll
    for (int ni = 0; ni < 2; ni++) uj[ni] = ldsw_read8(Uts, wc*32+ni*16+fr, ks*32+fq*8);
    #pragma unroll
    for (int mi = 0; mi < 4; mi++)
      #pragma unroll
      for (int ni = 0; ni < 2; ni++)
        acc2[mi][ni] = __builtin_amdgcn_mfma_f32_16x16x32_bf16(af[mi], uj[ni], acc2[mi][ni], 0,0,0);
  }
  // MFMA4: G[p][n] = (wU o U) . B
  f32x4 accS[2][4];
  #pragma unroll
  for (int mi = 0; mi < 2; mi++)
    #pragma unroll
    for (int ni = 0; ni < 4; ni++)
      accS[mi][ni] = (f32x4){0.f,0.f,0.f,0.f};
  #pragma unroll
  for (int ks = 0; ks < 4; ks++){
    bf16x8 au[2], bn[4];
    #pragma unroll
    for (int mi = 0; mi < 2; mi++){
      bf16x8 raw = ldsw_read8(Uts, wr*32+mi*16+fr, ks*32+fq*8);
      #pragma unroll
      for (int e = 0; e < 8; e++){
        float f = bf2f((unsigned short)raw[e]) * wUs[ks*32+fq*8+e];
        au[mi][e] = (short)f2bf(f);
      }
    }
    #pragma unroll
    for (int ni = 0; ni < 4; ni++) bn[ni] = ldsw_read8(BTs, wc*64+ni*16+fr, ks*32+fq*8);
    #pragma unroll
    for (int mi = 0; mi < 2; mi++)
      #pragma unroll
      for (int ni = 0; ni < 4; ni++)
        accS[mi][ni] = __builtin_amdgcn_mfma_f32_16x16x32_bf16(au[mi], bn[ni], accS[mi][ni], 0,0,0);
  }

  // stores: y_intra + D*x (ungated) and G
  #pragma unroll
  for (int mi = 0; mi < 4; mi++){
    #pragma unroll
    for (int ni = 0; ni < 2; ni++){
      #pragma unroll
      for (int r = 0; r < 4; r++){
        int t = wr*64+mi*16+fq*4+r;
        int p = wc*32+ni*16+fr;
        float xv = bf2f(ldsw_read1(Uts, p, t)) / fmaxf(dts[t], 1e-30f);
        float o = acc2[mi][ni][r] + Dh*xv;
        ybf[(size_t)(base + t)*4096 + h*64 + p] = f2bf(o);
      }
    }
  }
  #pragma unroll
  for (int mi = 0; mi < 2; mi++)
    #pragma unroll
    for (int ni = 0; ni < 4; ni++)
      #pragma unroll
      for (int r = 0; r < 4; r++){
        int p = wr*32+mi*16+fq*4+r;
        int n = wc*64+ni*16+fr;
        Gbuf[(size_t)blockIdx.x*8192 + p*128 + n] = f2bf(accS[mi][ni][r]);
      }
}

// ---------- pass B: scan over 8 chunks; Gbuf[c] <- S_prev(c), S = decEnd*S + G ----------
__global__ __launch_bounds__(256) void k_scanstate(
    const float* __restrict__ clcb, unsigned short* __restrict__ Gbuf)
{
  const int bh = blockIdx.x, tid = threadIdx.x;
  float S[32];
  #pragma unroll
  for (int q = 0; q < 32; q++) S[q] = 0.f;
  const size_t gbase = (size_t)bh*65536 + (size_t)tid*32;
  for (int c = 0; c < 8; c++){
    float decEnd = __expf(clcb[(size_t)bh*1024 + c*128 + 127]);
    unsigned short* p = Gbuf + gbase + (size_t)c*8192;
    bf16x8 g[4], s[4];
    #pragma unroll
    for (int q = 0; q < 4; q++) g[q] = *(const bf16x8*)(p + q*8);
    #pragma unroll
    for (int q = 0; q < 4; q++)
      #pragma unroll
      for (int e = 0; e < 8; e++) s[q][e] = (short)f2bf(S[q*8+e]);
    #pragma unroll
    for (int q = 0; q < 4; q++) *(bf16x8*)(p + q*8) = s[q];
    #pragma unroll
    for (int q = 0; q < 4; q++)
      #pragma unroll
      for (int e = 0; e < 8; e++)
        S[q*8+e] = decEnd*S[q*8+e] + bf2f((unsigned short)g[q][e]);
  }
}

// ---------- pass C: y = (y_intra + exp(clc_t) * C_t . S_prev^T) * silu(z) ----------
__global__ __launch_bounds__(256) void k_inter(
    const unsigned short* __restrict__ proj,
    const unsigned short* __restrict__ Cb2, const float* __restrict__ Cbias,
    const unsigned short* __restrict__ cosb, const unsigned short* __restrict__ sinb,
    const float* __restrict__ clcb, const unsigned short* __restrict__ Sprev,
    unsigned short* __restrict__ ybf)
{
  const int c = blockIdx.x & 7, bh = blockIdx.x >> 3;
  const int b = bh >> 6, h = bh & 63;
  const int tid = threadIdx.x, lane = tid & 63, wave = tid >> 6;
  const int wr = wave >> 1, wc = wave & 1;
  const int fr = lane & 15, fq = lane >> 4;

  __shared__ __align__(16) unsigned short Cs[128*128];
  __shared__ __align__(16) unsigned short Ss[64*128];
  __shared__ float expclcs[128], biasC[128];

  const int base = b*1024 + c*128;

  if (tid < 128){
    expclcs[tid] = __expf(clcb[(size_t)bh*1024 + c*128 + tid]);
    biasC[tid] = Cbias[h*128 + tid];
  }
  __syncthreads();

  // stage C (bias+rope)
  {
    const int t = tid >> 1, half = tid & 1;
    const int grow = base + t;
    const size_t roff = (size_t)grow*128 + half*64;
    if (half == 0){
      bf16x8 cc[4], sv[4];
      #pragma unroll
      for (int j = 0; j < 4; j++){
        cc[j] = *(const bf16x8*)(cosb + ((size_t)grow*64 + h)*32 + j*8);
        sv[j] = *(const bf16x8*)(sinb + ((size_t)grow*64 + h)*32 + j*8);
      }
      #pragma unroll
      for (int j = 0; j < 4; j++){
        bf16x8 vlo = *(const bf16x8*)(Cb2 + roff + j*8);
        bf16x8 vhi = *(const bf16x8*)(Cb2 + roff + 32 + j*8);
        bf16x8 olo, ohi;
        #pragma unroll
        for (int e = 0; e < 8; e++){
          float a = bf2f((unsigned short)vlo[e]) + biasC[j*8+e];
          float d = bf2f((unsigned short)vhi[e]) + biasC[32+j*8+e];
          float cf = bf2f((unsigned short)cc[j][e]);
          float sf = bf2f((unsigned short)sv[j][e]);
          olo[e] = (short)f2bf(a*cf - d*sf);
          ohi[e] = (short)f2bf(a*sf + d*cf);
        }
        ldsw_write8(Cs, t, j*8, olo);
        ldsw_write8(Cs, t, 32 + j*8, ohi);
      }
    } else {
      #pragma unroll
      for (int j = 0; j < 8; j++){
        bf16x8 v = *(const bf16x8*)(Cb2 + roff + j*8);
        bf16x8 o;
        #pragma unroll
        for (int e = 0; e < 8; e++) o[e] = (short)f2bf(bf2f((unsigned short)v[e]) + biasC[64+j*8+e]);
        ldsw_write8(Cs, t, 64 + j*8, o);
      }
    }
  }
  // stage S_prev (reg -> swizzled LDS)
  {
    const unsigned short* src = Sprev + (size_t)blockIdx.x*8192 + (size_t)tid*32;
    #pragma unroll
    for (int j = 0; j < 4; j++){
      bf16x8 v = *(const bf16x8*)(src + j*8);
      int f = tid*32 + j*8;
      ldsw_write8(Ss, f >> 7, f & 127, v);
    }
  }
  __syncthreads();

  // MFMA: Yinter[t][p] = C . S_prev^T
  f32x4 acc[4][2];
  #pragma unroll
  for (int mi = 0; mi < 4; mi++)
    #pragma unroll
    for (int ni = 0; ni < 2; ni++)
      acc[mi][ni] = (f32x4){0.f,0.f,0.f,0.f};
  #pragma unroll
  for (int ks = 0; ks < 4; ks++){
    bf16x8 af[4], sj[2];
    #pragma unroll
    for (int mi = 0; mi < 4; mi++) af[mi] = ldsw_read8(Cs, wr*64+mi*16+fr, ks*32+fq*8);
    #pragma unroll
    for (int ni = 0; ni < 2; ni++) sj[ni] = ldsw_read8(Ss, wc*32+ni*16+fr, ks*32+fq*8);
    #pragma unroll
    for (int mi = 0; mi < 4; mi++)
      #pragma unroll
      for (int ni = 0; ni < 2; ni++)
        acc[mi][ni] = __builtin_amdgcn_mfma_f32_16x16x32_bf16(af[mi], sj[ni], acc[mi][ni], 0,0,0);
  }

  // epilogue: y = (y_intra + expclc*Yinter) * silu(z)
  #pragma unroll
  for (int mi = 0; mi < 4; mi++){
    #pragma unroll
    for (int ni = 0; ni < 2; ni++){
      #pragma unroll
      for (int r = 0; r < 4; r++){
        int t = wr*64+mi*16+fq*4+r;
        int p = wc*32+ni*16+fr;
        size_t yoff = (size_t)(base + t)*4096 + h*64 + p;
        float y = bf2f(ybf[yoff]) + expclcs[t]*acc[mi][ni][r];
        float zv = bf2f(proj[(size_t)(base + t)*8704 + h*64 + p]);
        float sl = zv / (1.f + __expf(-zv));
        ybf[yoff] = f2bf(y * sl);
      }
    }
  }
}

// ---------- launch ----------
extern "C" void kernel_launch(void* const* d_in, const int* in_sizes, int n_in,
                              void* d_out, int out_size, void* d_ws, size_t ws_size,
                              hipStream_t stream)
{
  const float* hs    = (const float*)d_in[0];
  const float* w1    = (const float*)d_in[1];
  const float* dtb   = (const float*)d_in[2];
  const float* Bbias = (const float*)d_in[3];
  const float* Cbias = (const float*)d_in[4];
  const float* Bw    = (const float*)d_in[5];
  const float* Cw    = (const float*)d_in[6];
  const float* Dv    = (const float*)d_in[7];
  const float* wo    = (const float*)d_in[8];
  float* out = (float*)d_out;
  char* ws = (char*)d_ws;

  unsigned short* projbf = (unsigned short*)(ws + 0UL);
  unsigned short* W1bf   = (unsigned short*)(ws + 35651584UL);
  unsigned short* Gbuf   = W1bf;                                  // post-GEMM1
  unsigned short* Wobf   = W1bf;                                  // post-k_inter
  unsigned short* ybf    = (unsigned short*)(ws + 52428800UL);
  unsigned short* hsbf   = (unsigned short*)(ws + 71172096UL);
  unsigned short* cosb   = hsbf;                                  // post-GEMM1
  unsigned short* sinb   = (unsigned short*)(ws + 79560704UL);
  float* DTt    = (float*)(ws + 87949312UL);
  float* logdec = (float*)(ws + 88473600UL);
  float* lamt   = (float*)(ws + 88997888UL);
  float* clcb   = (float*)(ws + 89522176UL);
  float* gb     = (float*)(ws + 90046464UL);
  unsigned short* Bb2 = (unsigned short*)(ws + 90570752UL);
  unsigned short* Cb2 = (unsigned short*)(ws + 91095040UL);
  if (ws_size < 91619328UL) return;

  (void)in_sizes; (void)n_in; (void)out_size;

  k_f32_to_bf16<<<17344, 256, 0, stream>>>(w1, W1bf, 17760256L);
  k_f32_to_bf16<<<4096,  256, 0, stream>>>(hs, hsbf, 4194304L);
  // GEMM1: tiles 16x68; XCD partition 2x4 -> per-XCD 8rt x 17ct
  k_gemm_bt<true><<<1088, 256, 0, stream>>>(hsbf, W1bf, projbf, 2048, 8672, 8704, 2, 8, 17);
  k_rmsprep<<<2048, 128, 0, stream>>>(projbf, Bw, Cw, dtb, Bb2, Cb2, DTt, logdec, lamt);
  k_phase<<<128, 256, 0, stream>>>(projbf, DTt, logdec, lamt, clcb, gb, cosb, sinb);
  k_intra<<<1024, 256, 0, stream>>>(projbf, Bb2, Cb2, Bbias, Cbias,
                                    cosb, sinb, DTt, clcb, gb, lamt, Dv, ybf, Gbuf);
  k_scanstate<<<128, 256, 0, stream>>>(clcb, Gbuf);
  k_inter<<<1024, 256, 0, stream>>>(projbf, Cb2, Cbias, cosb, sinb, clcb, Gbuf, ybf);
  k_f32_to_bf16<<<8192, 256, 0, stream>>>(wo, Wobf, 8388608L);
  // GEMM2: tiles 16x16; XCD partition 4x2 -> per-XCD 4rt x 8ct
  k_gemm_bt<false><<<256, 256, 0, stream>>>(ybf, Wobf, out, 4096, 2048, 2048, 4, 4, 8);
}